// Round 5
// baseline (708.694 us; speedup 1.0000x reference)
//
#include <hip/hip_runtime.h>
#include <stdint.h>

#define HID 64
#define INCH 128
#define NGRAPH 64
#define KEEPP 0.7f
#define SCAN_B 256   // elements per scan block

// ---------------- Threefry-2x32 (JAX-compatible, 20 rounds) ----------------
__host__ __device__ inline void tf2x32(uint32_t k0, uint32_t k1,
                                       uint32_t& x0, uint32_t& x1) {
  const uint32_t ks2 = k0 ^ k1 ^ 0x1BD11BDAu;
#define ROTL32(v, d) (((v) << (d)) | ((v) >> (32 - (d))))
#define TF_RND(r) { x0 += x1; x1 = ROTL32(x1, r); x1 ^= x0; }
  x0 += k0; x1 += k1;
  TF_RND(13) TF_RND(15) TF_RND(26) TF_RND(6)
  x0 += k1;  x1 += ks2 + 1u;
  TF_RND(17) TF_RND(29) TF_RND(16) TF_RND(24)
  x0 += ks2; x1 += k0 + 2u;
  TF_RND(13) TF_RND(15) TF_RND(26) TF_RND(6)
  x0 += k0;  x1 += k1 + 3u;
  TF_RND(17) TF_RND(29) TF_RND(16) TF_RND(24)
  x0 += k1;  x1 += ks2 + 4u;
  TF_RND(13) TF_RND(15) TF_RND(26) TF_RND(6)
  x0 += ks2; x1 += k0 + 5u;
#undef TF_RND
#undef ROTL32
}

__device__ __forceinline__ bool keep_mask(uint32_t k0, uint32_t k1, uint32_t idx) {
  uint32_t x0 = 0u, x1 = idx;
  tf2x32(k0, k1, x0, x1);
  uint32_t bits = x0 ^ x1;
  float u = __uint_as_float((bits >> 9) | 0x3f800000u) - 1.0f;
  return u < KEEPP;
}

// ---------------- CSR build ----------------
__global__ void k_hist(const int* __restrict__ dst, int E, int* __restrict__ counts) {
  int e = blockIdx.x * blockDim.x + threadIdx.x;
  if (e < E) atomicAdd(&counts[dst[e]], 1);
}

__global__ void k_dinv(const int* __restrict__ counts, float* __restrict__ dinv, int N) {
  int i = blockIdx.x * blockDim.x + threadIdx.x;
  if (i < N) dinv[i] = rsqrtf((float)counts[i] + 1.0f);  // in-degree + self-loop
}

// ---- two-level scan: (1) block sums ----
__global__ __launch_bounds__(SCAN_B) void k_scan1(const int* __restrict__ counts,
                                                  int* __restrict__ bsum, int N) {
  int i = blockIdx.x * SCAN_B + threadIdx.x;
  int v = (i < N) ? counts[i] : 0;
  for (int off = 32; off > 0; off >>= 1) v += __shfl_down(v, off);
  __shared__ int ws[4];
  if ((threadIdx.x & 63) == 0) ws[threadIdx.x >> 6] = v;
  __syncthreads();
  if (threadIdx.x == 0) bsum[blockIdx.x] = ws[0] + ws[1] + ws[2] + ws[3];
}

// ---- (2) scan the block sums (B <= 1024) ----
__global__ __launch_bounds__(1024) void k_scan2(const int* __restrict__ bsum,
                                                int* __restrict__ bpre, int B) {
  __shared__ int s[1024];
  int tid = threadIdx.x;
  int v = (tid < B) ? bsum[tid] : 0;
  s[tid] = v;
  __syncthreads();
  for (int off = 1; off < 1024; off <<= 1) {
    int t = (tid >= off) ? s[tid - off] : 0;
    __syncthreads();
    s[tid] += t;
    __syncthreads();
  }
  if (tid < B) bpre[tid] = s[tid] - v;  // exclusive
}

// ---- (3) local scan + offset -> row_off, cursor ----
__global__ __launch_bounds__(SCAN_B) void k_scan3(const int* __restrict__ counts,
                                                  const int* __restrict__ bpre,
                                                  int* __restrict__ row_off,
                                                  int* __restrict__ cursor,
                                                  int N, int E) {
  __shared__ int s[SCAN_B];
  int tid = threadIdx.x;
  int i = blockIdx.x * SCAN_B + tid;
  int v = (i < N) ? counts[i] : 0;
  s[tid] = v;
  __syncthreads();
  for (int off = 1; off < SCAN_B; off <<= 1) {
    int t = (tid >= off) ? s[tid - off] : 0;
    __syncthreads();
    s[tid] += t;
    __syncthreads();
  }
  if (i < N) {
    int excl = bpre[blockIdx.x] + s[tid] - v;
    row_off[i] = excl;
    cursor[i] = excl;
  }
  if (i == 0) row_off[N] = E;
}

// ---------------- fused GEMM(layer1) + CSR build ----------------
// Blocks [0, gemm_blocks): C[N,64] = A[N,K] @ W[K,64]   (independent of CSR)
// Blocks [gemm_blocks, ..): scatter src indices into CSR slots (independent of GEMM)
// Both must complete before gather1 -> safe to fuse into one dispatch; the
// latency-bound build waves overlap with the VALU-bound GEMM waves (m114).
template <int K>
__global__ __launch_bounds__(256) void k_gemm_build(const float* __restrict__ A,
                                                    const float* __restrict__ W,
                                                    float* __restrict__ C, int N,
                                                    const int* __restrict__ src,
                                                    const int* __restrict__ dst,
                                                    int* __restrict__ cursor,
                                                    int* __restrict__ csr_src, int E,
                                                    int gemm_blocks) {
  if ((int)blockIdx.x >= gemm_blocks) {
    int e = ((int)blockIdx.x - gemm_blocks) * 256 + (int)threadIdx.x;
    if (e < E) {
      int s = src[e], d = dst[e];
      int pos = atomicAdd(&cursor[d], 1);
      csr_src[pos] = s;
    }
    return;
  }
  const int lane = threadIdx.x & 63;
  float w[K];
#pragma unroll
  for (int k = 0; k < K; ++k) w[k] = W[k * HID + lane];

  const int gwave = blockIdx.x * 4 + (threadIdx.x >> 6);
  const int nwaves = gemm_blocks * 4;
  const int npairs = (N + 1) >> 1;
  for (int p = gwave; p < npairs; p += nwaves) {
    const int r0 = __builtin_amdgcn_readfirstlane(2 * p);
    const bool has1 = (r0 + 1 < N);
    const float* __restrict__ A0 = A + (size_t)r0 * K;
    const float* __restrict__ A1 = A + (size_t)(r0 + (has1 ? 1 : 0)) * K;
    float acc0 = 0.0f, acc1 = 0.0f;
#pragma unroll
    for (int k = 0; k < K; ++k) {
      acc0 = fmaf(A0[k], w[k], acc0);
      acc1 = fmaf(A1[k], w[k], acc1);
    }
    C[(size_t)r0 * HID + lane] = acc0;
    if (has1) C[((size_t)r0 + 1) * HID + lane] = acc1;
  }
}

// ---------------- GEMM: C[N,64] = A[N,K] @ W[K,64] (standalone, layers 2/3) ----------------
template <int K>
__global__ __launch_bounds__(256) void k_gemm(const float* __restrict__ A,
                                              const float* __restrict__ W,
                                              float* __restrict__ C, int N) {
  const int lane = threadIdx.x & 63;
  float w[K];
#pragma unroll
  for (int k = 0; k < K; ++k) w[k] = W[k * HID + lane];

  const int gwave = blockIdx.x * 4 + (threadIdx.x >> 6);
  const int nwaves = gridDim.x * 4;
  const int npairs = (N + 1) >> 1;
  for (int p = gwave; p < npairs; p += nwaves) {
    const int r0 = __builtin_amdgcn_readfirstlane(2 * p);
    const bool has1 = (r0 + 1 < N);
    const float* __restrict__ A0 = A + (size_t)r0 * K;
    const float* __restrict__ A1 = A + (size_t)(r0 + (has1 ? 1 : 0)) * K;
    float acc0 = 0.0f, acc1 = 0.0f;
#pragma unroll
    for (int k = 0; k < K; ++k) {
      acc0 = fmaf(A0[k], w[k], acc0);
      acc1 = fmaf(A1[k], w[k], acc1);
    }
    C[(size_t)r0 * HID + lane] = acc0;
    if (has1) C[((size_t)r0 + 1) * HID + lane] = acc1;
  }
}

// ---------------- fused gather + self-loop + bias + relu + dropout ----------------
// w recomputed from dinv (wave-uniform scalar loads); bitwise-identical to the
// old csr_w product, so numerics are unchanged.
__global__ __launch_bounds__(256) void k_gather(const float* __restrict__ tmp,
                                                const int* __restrict__ row_off,
                                                const int* __restrict__ csr_src,
                                                const float* __restrict__ dinv,
                                                const float* __restrict__ bias,
                                                float* __restrict__ outh, int N,
                                                uint32_t k0, uint32_t k1) {
  const int node = blockIdx.x * 4 + (threadIdx.x >> 6);
  const int lane = threadIdx.x & 63;
  if (node >= N) return;
  const int beg = row_off[node];
  const int end = row_off[node + 1];
  const float dnode = dinv[node];
  float acc = 0.0f;
  int j = beg;
  for (; j + 1 < end; j += 2) {
    int s0 = csr_src[j], s1 = csr_src[j + 1];
    float w0 = dinv[s0] * dnode;
    float w1 = dinv[s1] * dnode;
    float v0 = tmp[(size_t)s0 * HID + lane];
    float v1 = tmp[(size_t)s1 * HID + lane];
    acc = fmaf(v0, w0, acc);
    acc = fmaf(v1, w1, acc);
  }
  if (j < end) {
    int s0 = csr_src[j];
    acc = fmaf(tmp[(size_t)s0 * HID + lane], dinv[s0] * dnode, acc);
  }
  const int idx = node * HID + lane;
  float v = acc + tmp[idx] * dnode * dnode + bias[lane];
  v = fmaxf(v, 0.0f);
  v = keep_mask(k0, k1, (uint32_t)idx) ? v / KEEPP : 0.0f;
  outh[idx] = v;
}

// ---------------- mean-pool partials ----------------
__global__ __launch_bounds__(256) void k_pool(const float* __restrict__ h,
                                              const int* __restrict__ batch,
                                              float* __restrict__ sums,
                                              float* __restrict__ cnts, int N) {
  __shared__ float ls[NGRAPH * HID];
  __shared__ float lc[NGRAPH];
  for (int i = threadIdx.x; i < NGRAPH * HID; i += 256) ls[i] = 0.0f;
  if (threadIdx.x < NGRAPH) lc[threadIdx.x] = 0.0f;
  __syncthreads();
  const int lane = threadIdx.x & 63;
  const int wave = threadIdx.x >> 6;
  int per = (N + gridDim.x - 1) / gridDim.x;
  int beg = blockIdx.x * per;
  int end = min(N, beg + per);
  for (int i = beg + wave; i < end; i += 4) {
    int g = batch[i];
    atomicAdd(&ls[g * HID + lane], h[(size_t)i * HID + lane]);
    if (lane == 0) atomicAdd(&lc[g], 1.0f);
  }
  __syncthreads();
  for (int i = threadIdx.x; i < NGRAPH * HID; i += 256)
    if (ls[i] != 0.0f) atomicAdd(&sums[i], ls[i]);
  if (threadIdx.x < NGRAPH && lc[threadIdx.x] != 0.0f)
    atomicAdd(&cnts[threadIdx.x], lc[threadIdx.x]);
}

// ---------------- MLP head (single block) ----------------
__global__ __launch_bounds__(256) void k_head(const float* __restrict__ sums,
                                              const float* __restrict__ cnts,
                                              const float* __restrict__ Wm1,
                                              const float* __restrict__ bm1,
                                              const float* __restrict__ Wm2,
                                              const float* __restrict__ bm2,
                                              float* __restrict__ out,
                                              uint32_t k0, uint32_t k1) {
  __shared__ float pooled[NGRAPH * HID];
  __shared__ float m[NGRAPH * HID];
  for (int i = threadIdx.x; i < NGRAPH * HID; i += 256) {
    int g = i >> 6;
    pooled[i] = sums[i] / fmaxf(cnts[g], 1.0f);
  }
  __syncthreads();
  for (int i = threadIdx.x; i < NGRAPH * HID; i += 256) {
    int g = i >> 6, j = i & 63;
    float acc = bm1[j];
#pragma unroll 8
    for (int k = 0; k < HID; ++k)
      acc = fmaf(pooled[g * HID + k], Wm1[k * HID + j], acc);
    acc = fmaxf(acc, 0.0f);
    m[i] = keep_mask(k0, k1, (uint32_t)i) ? acc / KEEPP : 0.0f;
  }
  __syncthreads();
  if (threadIdx.x < NGRAPH) {
    int g = threadIdx.x;
    float acc = bm2[0];
#pragma unroll 8
    for (int j = 0; j < HID; ++j)
      acc = fmaf(m[g * HID + j], Wm2[j], acc);
    out[g] = acc;
  }
}

extern "C" void kernel_launch(void* const* d_in, const int* in_sizes, int n_in,
                              void* d_out, int out_size, void* d_ws, size_t ws_size,
                              hipStream_t stream) {
  const float* x     = (const float*)d_in[0];
  const int*   ei    = (const int*)d_in[1];
  const int*   batch = (const int*)d_in[2];
  const float* W1 = (const float*)d_in[3];
  const float* b1 = (const float*)d_in[4];
  const float* W2 = (const float*)d_in[5];
  const float* b2 = (const float*)d_in[6];
  const float* W3 = (const float*)d_in[7];
  const float* b3 = (const float*)d_in[8];
  const float* Wm1 = (const float*)d_in[9];
  const float* bm1 = (const float*)d_in[10];
  const float* Wm2 = (const float*)d_in[11];
  const float* bm2 = (const float*)d_in[12];
  float* out = (float*)d_out;

  const int N = in_sizes[0] / INCH;
  const int E = in_sizes[1] / 2;
  const int* src = ei;
  const int* dst = ei + E;
  const int NB = (N + SCAN_B - 1) / SCAN_B;

  // workspace layout
  char* ws = (char*)d_ws;
  const size_t buf_bytes = (size_t)N * HID * sizeof(float);
  size_t off = 0;
  float* B0      = (float*)(ws + off); off += buf_bytes;
  float* B1      = (float*)(ws + off); off += buf_bytes;
  float* dinv    = (float*)(ws + off); off += (size_t)N * 4;
  int*   counts  = (int*)  (ws + off); off += (size_t)N * 4;
  int*   row_off = (int*)  (ws + off); off += ((size_t)N + 4) * 4;
  int*   cursor  = (int*)  (ws + off); off += (size_t)N * 4;
  int*   bsum    = (int*)  (ws + off); off += 1024 * 4;
  int*   bpre    = (int*)  (ws + off); off += 1024 * 4;
  int*   csr_src = (int*)  (ws + off); off += (size_t)E * 4;
  float* sums    = (float*)(ws + off); off += NGRAPH * HID * 4;
  float* cnts    = (float*)(ws + off); off += NGRAPH * 4;

  // dropout keys: dk[i] = threefry2x32((0,42),(0,i))
  uint32_t dk[4][2];
  for (uint32_t i = 0; i < 4; ++i) {
    uint32_t a = 0u, b = i;
    tf2x32(0u, 42u, a, b);
    dk[i][0] = a; dk[i][1] = b;
  }

  // ---- CSR prelude (hist + scan; build is fused with gemm1 below) ----
  hipMemsetAsync(counts, 0, (size_t)N * sizeof(int), stream);
  k_hist<<<(E + 255) / 256, 256, 0, stream>>>(dst, E, counts);
  k_dinv<<<(N + 255) / 256, 256, 0, stream>>>(counts, dinv, N);
  k_scan1<<<NB, SCAN_B, 0, stream>>>(counts, bsum, N);
  k_scan2<<<1, 1024, 0, stream>>>(bsum, bpre, NB);
  k_scan3<<<NB, SCAN_B, 0, stream>>>(counts, bpre, row_off, cursor, N, E);

  const int gemm_grid  = 2560;
  const int build_grid = (E + 255) / 256;
  const int gath_grid  = (N + 3) / 4;

  // ---- layer 1 (K=128) fused with CSR build ----
  k_gemm_build<INCH><<<gemm_grid + build_grid, 256, 0, stream>>>(
      x, W1, B0, N, src, dst, cursor, csr_src, E, gemm_grid);
  k_gather<<<gath_grid, 256, 0, stream>>>(B0, row_off, csr_src, dinv, b1,
                                          B1, N, dk[0][0], dk[0][1]);
  // ---- layer 2 (K=64) ----
  k_gemm<HID><<<gemm_grid, 256, 0, stream>>>(B1, W2, B0, N);
  k_gather<<<gath_grid, 256, 0, stream>>>(B0, row_off, csr_src, dinv, b2,
                                          B1, N, dk[1][0], dk[1][1]);
  // ---- layer 3 (K=64) ----
  k_gemm<HID><<<gemm_grid, 256, 0, stream>>>(B1, W3, B0, N);
  k_gather<<<gath_grid, 256, 0, stream>>>(B0, row_off, csr_src, dinv, b3,
                                          B1, N, dk[2][0], dk[2][1]);

  // ---- pool + head ----
  hipMemsetAsync(sums, 0, (NGRAPH * HID + NGRAPH) * sizeof(float), stream);
  k_pool<<<256, 256, 0, stream>>>(B1, batch, sums, cnts, N);
  k_head<<<1, 256, 0, stream>>>(sums, cnts, Wm1, bm1, Wm2, bm2, out,
                                dk[3][0], dk[3][1]);
  (void)n_in; (void)out_size; (void)ws_size;
}

// Round 6
// 536.034 us; speedup vs baseline: 1.3221x; 1.3221x over previous
//
#include <hip/hip_runtime.h>
#include <stdint.h>

#define HID 64
#define INCH 128
#define NGRAPH 64
#define KEEPP 0.7f
#define SCAN_B 256   // elements per scan block

// ---------------- Threefry-2x32 (JAX-compatible, 20 rounds) ----------------
__host__ __device__ inline void tf2x32(uint32_t k0, uint32_t k1,
                                       uint32_t& x0, uint32_t& x1) {
  const uint32_t ks2 = k0 ^ k1 ^ 0x1BD11BDAu;
#define ROTL32(v, d) (((v) << (d)) | ((v) >> (32 - (d))))
#define TF_RND(r) { x0 += x1; x1 = ROTL32(x1, r); x1 ^= x0; }
  x0 += k0; x1 += k1;
  TF_RND(13) TF_RND(15) TF_RND(26) TF_RND(6)
  x0 += k1;  x1 += ks2 + 1u;
  TF_RND(17) TF_RND(29) TF_RND(16) TF_RND(24)
  x0 += ks2; x1 += k0 + 2u;
  TF_RND(13) TF_RND(15) TF_RND(26) TF_RND(6)
  x0 += k0;  x1 += k1 + 3u;
  TF_RND(17) TF_RND(29) TF_RND(16) TF_RND(24)
  x0 += k1;  x1 += ks2 + 4u;
  TF_RND(13) TF_RND(15) TF_RND(26) TF_RND(6)
  x0 += ks2; x1 += k0 + 5u;
#undef TF_RND
#undef ROTL32
}

__device__ __forceinline__ bool keep_mask(uint32_t k0, uint32_t k1, uint32_t idx) {
  uint32_t x0 = 0u, x1 = idx;
  tf2x32(k0, k1, x0, x1);
  uint32_t bits = x0 ^ x1;
  float u = __uint_as_float((bits >> 9) | 0x3f800000u) - 1.0f;
  return u < KEEPP;
}

// ---------------- CSR build ----------------
__global__ void k_hist(const int* __restrict__ dst, int E, int* __restrict__ counts) {
  int e = blockIdx.x * blockDim.x + threadIdx.x;
  if (e < E) atomicAdd(&counts[dst[e]], 1);
}

__global__ void k_dinv(const int* __restrict__ counts, float* __restrict__ dinv, int N) {
  int i = blockIdx.x * blockDim.x + threadIdx.x;
  if (i < N) dinv[i] = rsqrtf((float)counts[i] + 1.0f);  // in-degree + self-loop
}

// ---- two-level scan: (1) block sums ----
__global__ __launch_bounds__(SCAN_B) void k_scan1(const int* __restrict__ counts,
                                                  int* __restrict__ bsum, int N) {
  int i = blockIdx.x * SCAN_B + threadIdx.x;
  int v = (i < N) ? counts[i] : 0;
  for (int off = 32; off > 0; off >>= 1) v += __shfl_down(v, off);
  __shared__ int ws[4];
  if ((threadIdx.x & 63) == 0) ws[threadIdx.x >> 6] = v;
  __syncthreads();
  if (threadIdx.x == 0) bsum[blockIdx.x] = ws[0] + ws[1] + ws[2] + ws[3];
}

// ---- (2) scan the block sums (B <= 1024) ----
__global__ __launch_bounds__(1024) void k_scan2(const int* __restrict__ bsum,
                                                int* __restrict__ bpre, int B) {
  __shared__ int s[1024];
  int tid = threadIdx.x;
  int v = (tid < B) ? bsum[tid] : 0;
  s[tid] = v;
  __syncthreads();
  for (int off = 1; off < 1024; off <<= 1) {
    int t = (tid >= off) ? s[tid - off] : 0;
    __syncthreads();
    s[tid] += t;
    __syncthreads();
  }
  if (tid < B) bpre[tid] = s[tid] - v;  // exclusive
}

// ---- (3) local scan + offset -> row_off, cursor ----
__global__ __launch_bounds__(SCAN_B) void k_scan3(const int* __restrict__ counts,
                                                  const int* __restrict__ bpre,
                                                  int* __restrict__ row_off,
                                                  int* __restrict__ cursor,
                                                  int N, int E) {
  __shared__ int s[SCAN_B];
  int tid = threadIdx.x;
  int i = blockIdx.x * SCAN_B + tid;
  int v = (i < N) ? counts[i] : 0;
  s[tid] = v;
  __syncthreads();
  for (int off = 1; off < SCAN_B; off <<= 1) {
    int t = (tid >= off) ? s[tid - off] : 0;
    __syncthreads();
    s[tid] += t;
    __syncthreads();
  }
  if (i < N) {
    int excl = bpre[blockIdx.x] + s[tid] - v;
    row_off[i] = excl;
    cursor[i] = excl;
  }
  if (i == 0) row_off[N] = E;
}

// ---- build packed CSR: one 8B store per edge (src, weight) ----
__global__ void k_build(const int* __restrict__ src, const int* __restrict__ dst,
                        const float* __restrict__ dinv, int* __restrict__ cursor,
                        int2* __restrict__ csr, int E) {
  int e = blockIdx.x * blockDim.x + threadIdx.x;
  if (e >= E) return;
  int s = src[e], d = dst[e];
  int pos = atomicAdd(&cursor[d], 1);
  csr[pos] = make_int2(s, __float_as_int(dinv[s] * dinv[d]));
}

// ---------------- GEMM: C[N,64] = A[N,K] @ W[K,64] ----------------
// Lane l holds W[:,l] in VGPRs; A-row values are wave-uniform -> scalar loads.
template <int K>
__global__ __launch_bounds__(256) void k_gemm(const float* __restrict__ A,
                                              const float* __restrict__ W,
                                              float* __restrict__ C, int N) {
  const int lane = threadIdx.x & 63;
  float w[K];
#pragma unroll
  for (int k = 0; k < K; ++k) w[k] = W[k * HID + lane];

  const int gwave = blockIdx.x * 4 + (threadIdx.x >> 6);
  const int nwaves = gridDim.x * 4;
  const int npairs = (N + 1) >> 1;
  for (int p = gwave; p < npairs; p += nwaves) {
    const int r0 = __builtin_amdgcn_readfirstlane(2 * p);
    const bool has1 = (r0 + 1 < N);
    const float* __restrict__ A0 = A + (size_t)r0 * K;
    const float* __restrict__ A1 = A + (size_t)(r0 + (has1 ? 1 : 0)) * K;
    float acc0 = 0.0f, acc1 = 0.0f;
#pragma unroll
    for (int k = 0; k < K; ++k) {
      acc0 = fmaf(A0[k], w[k], acc0);
      acc1 = fmaf(A1[k], w[k], acc1);
    }
    C[(size_t)r0 * HID + lane] = acc0;
    if (has1) C[((size_t)r0 + 1) * HID + lane] = acc1;
  }
}

// ---------------- fused gather + self-loop + bias + relu + dropout ----------------
// beg/end forced to SGPRs -> j is a scalar loop var; csr[j] becomes s_load,
// tmp row base becomes an SGPR base with lane offset (GEMM-style addressing).
__global__ __launch_bounds__(256) void k_gather(const float* __restrict__ tmp,
                                                const int* __restrict__ row_off,
                                                const int2* __restrict__ csr,
                                                const float* __restrict__ dinv,
                                                const float* __restrict__ bias,
                                                float* __restrict__ outh, int N,
                                                uint32_t k0, uint32_t k1) {
  const int node = blockIdx.x * 4 + (threadIdx.x >> 6);
  const int lane = threadIdx.x & 63;
  if (node >= N) return;
  const int beg = __builtin_amdgcn_readfirstlane(row_off[node]);
  const int end = __builtin_amdgcn_readfirstlane(row_off[node + 1]);
  float acc0 = 0.0f, acc1 = 0.0f;
  int j = beg;
  for (; j + 3 < end; j += 4) {
    int2 p0 = csr[j];
    int2 p1 = csr[j + 1];
    int2 p2 = csr[j + 2];
    int2 p3 = csr[j + 3];
    float v0 = tmp[(size_t)p0.x * HID + lane];
    float v1 = tmp[(size_t)p1.x * HID + lane];
    float v2 = tmp[(size_t)p2.x * HID + lane];
    float v3 = tmp[(size_t)p3.x * HID + lane];
    acc0 = fmaf(v0, __int_as_float(p0.y), acc0);
    acc1 = fmaf(v1, __int_as_float(p1.y), acc1);
    acc0 = fmaf(v2, __int_as_float(p2.y), acc0);
    acc1 = fmaf(v3, __int_as_float(p3.y), acc1);
  }
  for (; j < end; ++j) {
    int2 p0 = csr[j];
    acc0 = fmaf(tmp[(size_t)p0.x * HID + lane], __int_as_float(p0.y), acc0);
  }
  float acc = acc0 + acc1;
  const float dnode = dinv[node];
  const int idx = node * HID + lane;
  float v = acc + tmp[idx] * dnode * dnode + bias[lane];
  v = fmaxf(v, 0.0f);
  v = keep_mask(k0, k1, (uint32_t)idx) ? v / KEEPP : 0.0f;
  outh[idx] = v;
}

// ---------------- mean-pool partials ----------------
__global__ __launch_bounds__(256) void k_pool(const float* __restrict__ h,
                                              const int* __restrict__ batch,
                                              float* __restrict__ sums,
                                              float* __restrict__ cnts, int N) {
  __shared__ float ls[NGRAPH * HID];
  __shared__ float lc[NGRAPH];
  for (int i = threadIdx.x; i < NGRAPH * HID; i += 256) ls[i] = 0.0f;
  if (threadIdx.x < NGRAPH) lc[threadIdx.x] = 0.0f;
  __syncthreads();
  const int lane = threadIdx.x & 63;
  const int wave = threadIdx.x >> 6;
  int per = (N + gridDim.x - 1) / gridDim.x;
  int beg = blockIdx.x * per;
  int end = min(N, beg + per);
  for (int i = beg + wave; i < end; i += 4) {
    int g = batch[i];
    atomicAdd(&ls[g * HID + lane], h[(size_t)i * HID + lane]);
    if (lane == 0) atomicAdd(&lc[g], 1.0f);
  }
  __syncthreads();
  for (int i = threadIdx.x; i < NGRAPH * HID; i += 256)
    if (ls[i] != 0.0f) atomicAdd(&sums[i], ls[i]);
  if (threadIdx.x < NGRAPH && lc[threadIdx.x] != 0.0f)
    atomicAdd(&cnts[threadIdx.x], lc[threadIdx.x]);
}

// ---------------- MLP head (single block) ----------------
__global__ __launch_bounds__(256) void k_head(const float* __restrict__ sums,
                                              const float* __restrict__ cnts,
                                              const float* __restrict__ Wm1,
                                              const float* __restrict__ bm1,
                                              const float* __restrict__ Wm2,
                                              const float* __restrict__ bm2,
                                              float* __restrict__ out,
                                              uint32_t k0, uint32_t k1) {
  __shared__ float pooled[NGRAPH * HID];
  __shared__ float m[NGRAPH * HID];
  for (int i = threadIdx.x; i < NGRAPH * HID; i += 256) {
    int g = i >> 6;
    pooled[i] = sums[i] / fmaxf(cnts[g], 1.0f);
  }
  __syncthreads();
  for (int i = threadIdx.x; i < NGRAPH * HID; i += 256) {
    int g = i >> 6, j = i & 63;
    float acc = bm1[j];
#pragma unroll 8
    for (int k = 0; k < HID; ++k)
      acc = fmaf(pooled[g * HID + k], Wm1[k * HID + j], acc);
    acc = fmaxf(acc, 0.0f);
    m[i] = keep_mask(k0, k1, (uint32_t)i) ? acc / KEEPP : 0.0f;
  }
  __syncthreads();
  if (threadIdx.x < NGRAPH) {
    int g = threadIdx.x;
    float acc = bm2[0];
#pragma unroll 8
    for (int j = 0; j < HID; ++j)
      acc = fmaf(m[g * HID + j], Wm2[j], acc);
    out[g] = acc;
  }
}

extern "C" void kernel_launch(void* const* d_in, const int* in_sizes, int n_in,
                              void* d_out, int out_size, void* d_ws, size_t ws_size,
                              hipStream_t stream) {
  const float* x     = (const float*)d_in[0];
  const int*   ei    = (const int*)d_in[1];
  const int*   batch = (const int*)d_in[2];
  const float* W1 = (const float*)d_in[3];
  const float* b1 = (const float*)d_in[4];
  const float* W2 = (const float*)d_in[5];
  const float* b2 = (const float*)d_in[6];
  const float* W3 = (const float*)d_in[7];
  const float* b3 = (const float*)d_in[8];
  const float* Wm1 = (const float*)d_in[9];
  const float* bm1 = (const float*)d_in[10];
  const float* Wm2 = (const float*)d_in[11];
  const float* bm2 = (const float*)d_in[12];
  float* out = (float*)d_out;

  const int N = in_sizes[0] / INCH;
  const int E = in_sizes[1] / 2;
  const int* src = ei;
  const int* dst = ei + E;
  const int NB = (N + SCAN_B - 1) / SCAN_B;

  // workspace layout (all chunks 8B-aligned)
  char* ws = (char*)d_ws;
  const size_t buf_bytes = (size_t)N * HID * sizeof(float);
  size_t off = 0;
  float* B0      = (float*)(ws + off); off += buf_bytes;
  float* B1      = (float*)(ws + off); off += buf_bytes;
  float* dinv    = (float*)(ws + off); off += (size_t)N * 4;
  int*   counts  = (int*)  (ws + off); off += (size_t)N * 4;
  int*   row_off = (int*)  (ws + off); off += ((size_t)N + 4) * 4;
  int*   cursor  = (int*)  (ws + off); off += (size_t)N * 4;
  int*   bsum    = (int*)  (ws + off); off += 1024 * 4;
  int*   bpre    = (int*)  (ws + off); off += 1024 * 4;
  int2*  csr     = (int2*) (ws + off); off += (size_t)E * 8;
  float* sums    = (float*)(ws + off); off += NGRAPH * HID * 4;
  float* cnts    = (float*)(ws + off); off += NGRAPH * 4;

  // dropout keys: dk[i] = threefry2x32((0,42),(0,i))
  uint32_t dk[4][2];
  for (uint32_t i = 0; i < 4; ++i) {
    uint32_t a = 0u, b = i;
    tf2x32(0u, 42u, a, b);
    dk[i][0] = a; dk[i][1] = b;
  }

  // ---- CSR build (reused for all 3 layers) ----
  hipMemsetAsync(counts, 0, (size_t)N * sizeof(int), stream);
  k_hist<<<(E + 255) / 256, 256, 0, stream>>>(dst, E, counts);
  k_dinv<<<(N + 255) / 256, 256, 0, stream>>>(counts, dinv, N);
  k_scan1<<<NB, SCAN_B, 0, stream>>>(counts, bsum, N);
  k_scan2<<<1, 1024, 0, stream>>>(bsum, bpre, NB);
  k_scan3<<<NB, SCAN_B, 0, stream>>>(counts, bpre, row_off, cursor, N, E);
  k_build<<<(E + 255) / 256, 256, 0, stream>>>(src, dst, dinv, cursor, csr, E);

  const int gemm_grid = 2560;
  const int gath_grid = (N + 3) / 4;

  // ---- layer 1 (K=128) ----
  k_gemm<INCH><<<gemm_grid, 256, 0, stream>>>(x, W1, B0, N);
  k_gather<<<gath_grid, 256, 0, stream>>>(B0, row_off, csr, dinv, b1,
                                          B1, N, dk[0][0], dk[0][1]);
  // ---- layer 2 (K=64) ----
  k_gemm<HID><<<gemm_grid, 256, 0, stream>>>(B1, W2, B0, N);
  k_gather<<<gath_grid, 256, 0, stream>>>(B0, row_off, csr, dinv, b2,
                                          B1, N, dk[1][0], dk[1][1]);
  // ---- layer 3 (K=64) ----
  k_gemm<HID><<<gemm_grid, 256, 0, stream>>>(B1, W3, B0, N);
  k_gather<<<gath_grid, 256, 0, stream>>>(B0, row_off, csr, dinv, b3,
                                          B1, N, dk[2][0], dk[2][1]);

  // ---- pool + head ----
  hipMemsetAsync(sums, 0, (NGRAPH * HID + NGRAPH) * sizeof(float), stream);
  k_pool<<<256, 256, 0, stream>>>(B1, batch, sums, cnts, N);
  k_head<<<1, 256, 0, stream>>>(sums, cnts, Wm1, bm1, Wm2, bm2, out,
                                dk[3][0], dk[3][1]);
  (void)n_in; (void)out_size; (void)ws_size;
}

// Round 7
// 476.046 us; speedup vs baseline: 1.4887x; 1.1260x over previous
//
#include <hip/hip_runtime.h>
#include <stdint.h>

#define HID 64
#define INCH 128
#define NGRAPH 64
#define KEEPP 0.7f
#define SCAN_B 256   // elements per scan block

typedef __attribute__((ext_vector_type(8))) short short8;   // 8 bf16 = 4 VGPRs
typedef __attribute__((ext_vector_type(4))) float floatx4;  // MFMA acc

// ---------------- Threefry-2x32 (JAX-compatible, 20 rounds) ----------------
__host__ __device__ inline void tf2x32(uint32_t k0, uint32_t k1,
                                       uint32_t& x0, uint32_t& x1) {
  const uint32_t ks2 = k0 ^ k1 ^ 0x1BD11BDAu;
#define ROTL32(v, d) (((v) << (d)) | ((v) >> (32 - (d))))
#define TF_RND(r) { x0 += x1; x1 = ROTL32(x1, r); x1 ^= x0; }
  x0 += k0; x1 += k1;
  TF_RND(13) TF_RND(15) TF_RND(26) TF_RND(6)
  x0 += k1;  x1 += ks2 + 1u;
  TF_RND(17) TF_RND(29) TF_RND(16) TF_RND(24)
  x0 += ks2; x1 += k0 + 2u;
  TF_RND(13) TF_RND(15) TF_RND(26) TF_RND(6)
  x0 += k0;  x1 += k1 + 3u;
  TF_RND(17) TF_RND(29) TF_RND(16) TF_RND(24)
  x0 += k1;  x1 += ks2 + 4u;
  TF_RND(13) TF_RND(15) TF_RND(26) TF_RND(6)
  x0 += ks2; x1 += k0 + 5u;
#undef TF_RND
#undef ROTL32
}

__device__ __forceinline__ bool keep_mask(uint32_t k0, uint32_t k1, uint32_t idx) {
  uint32_t x0 = 0u, x1 = idx;
  tf2x32(k0, k1, x0, x1);
  uint32_t bits = x0 ^ x1;
  float u = __uint_as_float((bits >> 9) | 0x3f800000u) - 1.0f;
  return u < KEEPP;
}

// ---------------- CSR build ----------------
__global__ void k_hist(const int* __restrict__ dst, int E, int* __restrict__ counts) {
  int e = blockIdx.x * blockDim.x + threadIdx.x;
  if (e < E) atomicAdd(&counts[dst[e]], 1);
}

__global__ void k_dinv(const int* __restrict__ counts, float* __restrict__ dinv, int N) {
  int i = blockIdx.x * blockDim.x + threadIdx.x;
  if (i < N) dinv[i] = rsqrtf((float)counts[i] + 1.0f);  // in-degree + self-loop
}

// ---- two-level scan: (1) block sums ----
__global__ __launch_bounds__(SCAN_B) void k_scan1(const int* __restrict__ counts,
                                                  int* __restrict__ bsum, int N) {
  int i = blockIdx.x * SCAN_B + threadIdx.x;
  int v = (i < N) ? counts[i] : 0;
  for (int off = 32; off > 0; off >>= 1) v += __shfl_down(v, off);
  __shared__ int ws[4];
  if ((threadIdx.x & 63) == 0) ws[threadIdx.x >> 6] = v;
  __syncthreads();
  if (threadIdx.x == 0) bsum[blockIdx.x] = ws[0] + ws[1] + ws[2] + ws[3];
}

// ---- (2) scan the block sums (B <= 1024) ----
__global__ __launch_bounds__(1024) void k_scan2(const int* __restrict__ bsum,
                                                int* __restrict__ bpre, int B) {
  __shared__ int s[1024];
  int tid = threadIdx.x;
  int v = (tid < B) ? bsum[tid] : 0;
  s[tid] = v;
  __syncthreads();
  for (int off = 1; off < 1024; off <<= 1) {
    int t = (tid >= off) ? s[tid - off] : 0;
    __syncthreads();
    s[tid] += t;
    __syncthreads();
  }
  if (tid < B) bpre[tid] = s[tid] - v;  // exclusive
}

// ---- (3) local scan + offset -> row_off, cursor ----
__global__ __launch_bounds__(SCAN_B) void k_scan3(const int* __restrict__ counts,
                                                  const int* __restrict__ bpre,
                                                  int* __restrict__ row_off,
                                                  int* __restrict__ cursor,
                                                  int N, int E) {
  __shared__ int s[SCAN_B];
  int tid = threadIdx.x;
  int i = blockIdx.x * SCAN_B + tid;
  int v = (i < N) ? counts[i] : 0;
  s[tid] = v;
  __syncthreads();
  for (int off = 1; off < SCAN_B; off <<= 1) {
    int t = (tid >= off) ? s[tid - off] : 0;
    __syncthreads();
    s[tid] += t;
    __syncthreads();
  }
  if (i < N) {
    int excl = bpre[blockIdx.x] + s[tid] - v;
    row_off[i] = excl;
    cursor[i] = excl;
  }
  if (i == 0) row_off[N] = E;
}

// ---- build packed CSR: one 8B store per edge (src, weight) ----
__global__ void k_build(const int* __restrict__ src, const int* __restrict__ dst,
                        const float* __restrict__ dinv, int* __restrict__ cursor,
                        int2* __restrict__ csr, int E) {
  int e = blockIdx.x * blockDim.x + threadIdx.x;
  if (e >= E) return;
  int s = src[e], d = dst[e];
  int pos = atomicAdd(&cursor[d], 1);
  csr[pos] = make_int2(s, __float_as_int(dinv[s] * dinv[d]));
}

// ---------------- W pre-split into MFMA B-fragment layout ----------------
// Frag entry i = (kc*4 + ct)*64 + lane holds 8 bf16: W[kc*32 + (lane>>4)*8 + j]
// [ct*16 + (lane&15)], split into hi (bf16 truncation) and lo (residual bf16).
__global__ __launch_bounds__(256) void k_wsplit(const float* __restrict__ W,
                                                short8* __restrict__ Wh,
                                                short8* __restrict__ Wl, int KC) {
  int i = blockIdx.x * 256 + threadIdx.x;
  int total = KC * 4 * 64;
  if (i >= total) return;
  int lane = i & 63, f = i >> 6;
  int kc = f >> 2, ct = f & 3;
  int kbase = kc * 32 + ((lane >> 4) << 3);
  int n = ct * 16 + (lane & 15);
  short8 h, l;
#pragma unroll
  for (int j = 0; j < 8; ++j) {
    float w = W[(size_t)(kbase + j) * HID + n];
    uint32_t u = __float_as_uint(w);
    h[j] = (short)(u >> 16);
    float r = w - __uint_as_float(u & 0xFFFF0000u);
    l[j] = (short)(__float_as_uint(r) >> 16);
  }
  Wh[i] = h;
  Wl[i] = l;
}

// ---------------- MFMA GEMM: C[N,64] = A[N,K] @ W[K,64] ----------------
// 3-term bf16 split: A*W ~= Ah*Wh + Ah*Wl + Al*Wh (error ~2^-16 rel).
// Block = 4 waves = 64 rows; wave = 16 rows x 64 cols = 4 C-tiles of 16x16.
template <int K>
__global__ __launch_bounds__(256) void k_mgemm(const float* __restrict__ A,
                                               const short8* __restrict__ Wh,
                                               const short8* __restrict__ Wl,
                                               float* __restrict__ C, int N) {
  constexpr int KC = K / 32;
  const int lane = threadIdx.x & 63;
  const int wv = threadIdx.x >> 6;
  const int m = lane & 15;   // A row-in-16 / C col-in-16
  const int q = lane >> 4;   // quad: A k-offset q*8 / C row-group q*4
  const int row0 = blockIdx.x * 64 + wv * 16;
  if (row0 >= N) return;
  const int arow = min(row0 + m, N - 1);
  const float* __restrict__ ap = A + (size_t)arow * K + (q << 3);

  floatx4 acc[4];
#pragma unroll
  for (int ct = 0; ct < 4; ++ct) acc[ct] = (floatx4){0.f, 0.f, 0.f, 0.f};

#pragma unroll
  for (int kc = 0; kc < KC; ++kc) {
    const floatx4* apv = (const floatx4*)(ap + kc * 32);
    floatx4 x0 = apv[0];
    floatx4 x1 = apv[1];
    short8 ah, al;
#pragma unroll
    for (int j = 0; j < 4; ++j) {
      uint32_t u = __float_as_uint(x0[j]);
      ah[j] = (short)(u >> 16);
      float r = x0[j] - __uint_as_float(u & 0xFFFF0000u);
      al[j] = (short)(__float_as_uint(r) >> 16);
    }
#pragma unroll
    for (int j = 0; j < 4; ++j) {
      uint32_t u = __float_as_uint(x1[j]);
      ah[4 + j] = (short)(u >> 16);
      float r = x1[j] - __uint_as_float(u & 0xFFFF0000u);
      al[4 + j] = (short)(__float_as_uint(r) >> 16);
    }
#pragma unroll
    for (int ct = 0; ct < 4; ++ct) {
      short8 bh = Wh[(kc * 4 + ct) * 64 + lane];
      short8 bl = Wl[(kc * 4 + ct) * 64 + lane];
      acc[ct] = __builtin_amdgcn_mfma_f32_16x16x32_bf16(ah, bh, acc[ct], 0, 0, 0);
      acc[ct] = __builtin_amdgcn_mfma_f32_16x16x32_bf16(ah, bl, acc[ct], 0, 0, 0);
      acc[ct] = __builtin_amdgcn_mfma_f32_16x16x32_bf16(al, bh, acc[ct], 0, 0, 0);
    }
  }

  float* __restrict__ cp = C + (size_t)row0 * HID;
#pragma unroll
  for (int ct = 0; ct < 4; ++ct)
#pragma unroll
    for (int r = 0; r < 4; ++r) {
      int rr = (q << 2) + r;
      if (row0 + rr < N) cp[(size_t)rr * HID + ct * 16 + m] = acc[ct][r];
    }
}

// ---------------- fused gather + self-loop + bias + relu + dropout ----------------
__global__ __launch_bounds__(256) void k_gather(const float* __restrict__ tmp,
                                                const int* __restrict__ row_off,
                                                const int2* __restrict__ csr,
                                                const float* __restrict__ dinv,
                                                const float* __restrict__ bias,
                                                float* __restrict__ outh, int N,
                                                uint32_t k0, uint32_t k1) {
  const int node = blockIdx.x * 4 + (threadIdx.x >> 6);
  const int lane = threadIdx.x & 63;
  if (node >= N) return;
  const int beg = __builtin_amdgcn_readfirstlane(row_off[node]);
  const int end = __builtin_amdgcn_readfirstlane(row_off[node + 1]);
  float acc0 = 0.0f, acc1 = 0.0f;
  int j = beg;
  for (; j + 3 < end; j += 4) {
    int2 p0 = csr[j];
    int2 p1 = csr[j + 1];
    int2 p2 = csr[j + 2];
    int2 p3 = csr[j + 3];
    float v0 = tmp[(size_t)p0.x * HID + lane];
    float v1 = tmp[(size_t)p1.x * HID + lane];
    float v2 = tmp[(size_t)p2.x * HID + lane];
    float v3 = tmp[(size_t)p3.x * HID + lane];
    acc0 = fmaf(v0, __int_as_float(p0.y), acc0);
    acc1 = fmaf(v1, __int_as_float(p1.y), acc1);
    acc0 = fmaf(v2, __int_as_float(p2.y), acc0);
    acc1 = fmaf(v3, __int_as_float(p3.y), acc1);
  }
  for (; j < end; ++j) {
    int2 p0 = csr[j];
    acc0 = fmaf(tmp[(size_t)p0.x * HID + lane], __int_as_float(p0.y), acc0);
  }
  float acc = acc0 + acc1;
  const float dnode = dinv[node];
  const int idx = node * HID + lane;
  float v = acc + tmp[idx] * dnode * dnode + bias[lane];
  v = fmaxf(v, 0.0f);
  v = keep_mask(k0, k1, (uint32_t)idx) ? v / KEEPP : 0.0f;
  outh[idx] = v;
}

// ---------------- mean-pool partials ----------------
__global__ __launch_bounds__(256) void k_pool(const float* __restrict__ h,
                                              const int* __restrict__ batch,
                                              float* __restrict__ sums,
                                              float* __restrict__ cnts, int N) {
  __shared__ float ls[NGRAPH * HID];
  __shared__ float lc[NGRAPH];
  for (int i = threadIdx.x; i < NGRAPH * HID; i += 256) ls[i] = 0.0f;
  if (threadIdx.x < NGRAPH) lc[threadIdx.x] = 0.0f;
  __syncthreads();
  const int lane = threadIdx.x & 63;
  const int wave = threadIdx.x >> 6;
  int per = (N + gridDim.x - 1) / gridDim.x;
  int beg = blockIdx.x * per;
  int end = min(N, beg + per);
  for (int i = beg + wave; i < end; i += 4) {
    int g = batch[i];
    atomicAdd(&ls[g * HID + lane], h[(size_t)i * HID + lane]);
    if (lane == 0) atomicAdd(&lc[g], 1.0f);
  }
  __syncthreads();
  for (int i = threadIdx.x; i < NGRAPH * HID; i += 256)
    if (ls[i] != 0.0f) atomicAdd(&sums[i], ls[i]);
  if (threadIdx.x < NGRAPH && lc[threadIdx.x] != 0.0f)
    atomicAdd(&cnts[threadIdx.x], lc[threadIdx.x]);
}

// ---------------- MLP head (single block) ----------------
__global__ __launch_bounds__(256) void k_head(const float* __restrict__ sums,
                                              const float* __restrict__ cnts,
                                              const float* __restrict__ Wm1,
                                              const float* __restrict__ bm1,
                                              const float* __restrict__ Wm2,
                                              const float* __restrict__ bm2,
                                              float* __restrict__ out,
                                              uint32_t k0, uint32_t k1) {
  __shared__ float pooled[NGRAPH * HID];
  __shared__ float m[NGRAPH * HID];
  for (int i = threadIdx.x; i < NGRAPH * HID; i += 256) {
    int g = i >> 6;
    pooled[i] = sums[i] / fmaxf(cnts[g], 1.0f);
  }
  __syncthreads();
  for (int i = threadIdx.x; i < NGRAPH * HID; i += 256) {
    int g = i >> 6, j = i & 63;
    float acc = bm1[j];
#pragma unroll 8
    for (int k = 0; k < HID; ++k)
      acc = fmaf(pooled[g * HID + k], Wm1[k * HID + j], acc);
    acc = fmaxf(acc, 0.0f);
    m[i] = keep_mask(k0, k1, (uint32_t)i) ? acc / KEEPP : 0.0f;
  }
  __syncthreads();
  if (threadIdx.x < NGRAPH) {
    int g = threadIdx.x;
    float acc = bm2[0];
#pragma unroll 8
    for (int j = 0; j < HID; ++j)
      acc = fmaf(m[g * HID + j], Wm2[j], acc);
    out[g] = acc;
  }
}

extern "C" void kernel_launch(void* const* d_in, const int* in_sizes, int n_in,
                              void* d_out, int out_size, void* d_ws, size_t ws_size,
                              hipStream_t stream) {
  const float* x     = (const float*)d_in[0];
  const int*   ei    = (const int*)d_in[1];
  const int*   batch = (const int*)d_in[2];
  const float* W1 = (const float*)d_in[3];
  const float* b1 = (const float*)d_in[4];
  const float* W2 = (const float*)d_in[5];
  const float* b2 = (const float*)d_in[6];
  const float* W3 = (const float*)d_in[7];
  const float* b3 = (const float*)d_in[8];
  const float* Wm1 = (const float*)d_in[9];
  const float* bm1 = (const float*)d_in[10];
  const float* Wm2 = (const float*)d_in[11];
  const float* bm2 = (const float*)d_in[12];
  float* out = (float*)d_out;

  const int N = in_sizes[0] / INCH;
  const int E = in_sizes[1] / 2;
  const int* src = ei;
  const int* dst = ei + E;
  const int NB = (N + SCAN_B - 1) / SCAN_B;

  // workspace layout (all chunks >=16B-aligned)
  char* ws = (char*)d_ws;
  const size_t buf_bytes = (size_t)N * HID * sizeof(float);
  size_t off = 0;
  float* B0      = (float*)(ws + off); off += buf_bytes;
  float* B1      = (float*)(ws + off); off += buf_bytes;
  float* dinv    = (float*)(ws + off); off += (size_t)N * 4;
  int*   counts  = (int*)  (ws + off); off += (size_t)N * 4;
  int*   row_off = (int*)  (ws + off); off += ((size_t)N + 4) * 4;
  int*   cursor  = (int*)  (ws + off); off += (size_t)N * 4;
  int*   bsum    = (int*)  (ws + off); off += 1024 * 4;
  int*   bpre    = (int*)  (ws + off); off += 1024 * 4;
  int2*  csr     = (int2*) (ws + off); off += (size_t)E * 8;
  float* sums    = (float*)(ws + off); off += NGRAPH * HID * 4;
  float* cnts    = (float*)(ws + off); off += NGRAPH * 4;
  off = (off + 15) & ~(size_t)15;
  short8* Wh1 = (short8*)(ws + off); off += 1024 * 16;  // KC=4: 4*4*64 entries
  short8* Wl1 = (short8*)(ws + off); off += 1024 * 16;
  short8* Wh2 = (short8*)(ws + off); off += 512 * 16;   // KC=2
  short8* Wl2 = (short8*)(ws + off); off += 512 * 16;
  short8* Wh3 = (short8*)(ws + off); off += 512 * 16;
  short8* Wl3 = (short8*)(ws + off); off += 512 * 16;

  // dropout keys: dk[i] = threefry2x32((0,42),(0,i))
  uint32_t dk[4][2];
  for (uint32_t i = 0; i < 4; ++i) {
    uint32_t a = 0u, b = i;
    tf2x32(0u, 42u, a, b);
    dk[i][0] = a; dk[i][1] = b;
  }

  // ---- W splits (independent; schedule first) ----
  k_wsplit<<<4, 256, 0, stream>>>(W1, Wh1, Wl1, 4);
  k_wsplit<<<2, 256, 0, stream>>>(W2, Wh2, Wl2, 2);
  k_wsplit<<<2, 256, 0, stream>>>(W3, Wh3, Wl3, 2);

  // ---- CSR build (reused for all 3 layers) ----
  hipMemsetAsync(counts, 0, (size_t)N * sizeof(int), stream);
  k_hist<<<(E + 255) / 256, 256, 0, stream>>>(dst, E, counts);
  k_dinv<<<(N + 255) / 256, 256, 0, stream>>>(counts, dinv, N);
  k_scan1<<<NB, SCAN_B, 0, stream>>>(counts, bsum, N);
  k_scan2<<<1, 1024, 0, stream>>>(bsum, bpre, NB);
  k_scan3<<<NB, SCAN_B, 0, stream>>>(counts, bpre, row_off, cursor, N, E);
  k_build<<<(E + 255) / 256, 256, 0, stream>>>(src, dst, dinv, cursor, csr, E);

  const int mg_grid   = (N + 63) / 64;
  const int gath_grid = (N + 3) / 4;

  // ---- layer 1 (K=128) ----
  k_mgemm<INCH><<<mg_grid, 256, 0, stream>>>(x, Wh1, Wl1, B0, N);
  k_gather<<<gath_grid, 256, 0, stream>>>(B0, row_off, csr, dinv, b1,
                                          B1, N, dk[0][0], dk[0][1]);
  // ---- layer 2 (K=64) ----
  k_mgemm<HID><<<mg_grid, 256, 0, stream>>>(B1, Wh2, Wl2, B0, N);
  k_gather<<<gath_grid, 256, 0, stream>>>(B0, row_off, csr, dinv, b2,
                                          B1, N, dk[1][0], dk[1][1]);
  // ---- layer 3 (K=64) ----
  k_mgemm<HID><<<mg_grid, 256, 0, stream>>>(B1, Wh3, Wl3, B0, N);
  k_gather<<<gath_grid, 256, 0, stream>>>(B0, row_off, csr, dinv, b3,
                                          B1, N, dk[2][0], dk[2][1]);

  // ---- pool + head ----
  hipMemsetAsync(sums, 0, (NGRAPH * HID + NGRAPH) * sizeof(float), stream);
  k_pool<<<256, 256, 0, stream>>>(B1, batch, sums, cnts, N);
  k_head<<<1, 256, 0, stream>>>(sums, cnts, Wm1, bm1, Wm2, bm2, out,
                                dk[3][0], dk[3][1]);
  (void)n_in; (void)out_size; (void)ws_size;
}

// Round 8
// 465.304 us; speedup vs baseline: 1.5231x; 1.0231x over previous
//
#include <hip/hip_runtime.h>
#include <stdint.h>

#define HID 64
#define INCH 128
#define NGRAPH 64
#define KEEPP 0.7f
#define SCAN_B 256   // elements per scan block

typedef __attribute__((ext_vector_type(8))) short short8;   // 8 bf16 = 4 VGPRs
typedef __attribute__((ext_vector_type(4))) float floatx4;  // MFMA acc

// ---------------- Threefry-2x32 (JAX-compatible, 20 rounds) ----------------
__host__ __device__ inline void tf2x32(uint32_t k0, uint32_t k1,
                                       uint32_t& x0, uint32_t& x1) {
  const uint32_t ks2 = k0 ^ k1 ^ 0x1BD11BDAu;
#define ROTL32(v, d) (((v) << (d)) | ((v) >> (32 - (d))))
#define TF_RND(r) { x0 += x1; x1 = ROTL32(x1, r); x1 ^= x0; }
  x0 += k0; x1 += k1;
  TF_RND(13) TF_RND(15) TF_RND(26) TF_RND(6)
  x0 += k1;  x1 += ks2 + 1u;
  TF_RND(17) TF_RND(29) TF_RND(16) TF_RND(24)
  x0 += ks2; x1 += k0 + 2u;
  TF_RND(13) TF_RND(15) TF_RND(26) TF_RND(6)
  x0 += k0;  x1 += k1 + 3u;
  TF_RND(17) TF_RND(29) TF_RND(16) TF_RND(24)
  x0 += k1;  x1 += ks2 + 4u;
  TF_RND(13) TF_RND(15) TF_RND(26) TF_RND(6)
  x0 += ks2; x1 += k0 + 5u;
#undef TF_RND
#undef ROTL32
}

__device__ __forceinline__ bool keep_mask(uint32_t k0, uint32_t k1, uint32_t idx) {
  uint32_t x0 = 0u, x1 = idx;
  tf2x32(k0, k1, x0, x1);
  uint32_t bits = x0 ^ x1;
  float u = __uint_as_float((bits >> 9) | 0x3f800000u) - 1.0f;
  return u < KEEPP;
}

// ---------------- CSR build prelude ----------------
__global__ void k_hist(const int* __restrict__ dst, int E, int* __restrict__ counts) {
  int e = blockIdx.x * blockDim.x + threadIdx.x;
  if (e < E) atomicAdd(&counts[dst[e]], 1);
}

// ---- scan stage 1 + dinv fused (both read counts[i]) ----
__global__ __launch_bounds__(SCAN_B) void k_scan1d(const int* __restrict__ counts,
                                                   int* __restrict__ bsum,
                                                   float* __restrict__ dinv, int N) {
  int i = blockIdx.x * SCAN_B + threadIdx.x;
  int v = 0;
  if (i < N) {
    v = counts[i];
    dinv[i] = rsqrtf((float)v + 1.0f);  // in-degree + self-loop
  }
  int r = v;
  for (int off = 32; off > 0; off >>= 1) r += __shfl_down(r, off);
  __shared__ int ws[4];
  if ((threadIdx.x & 63) == 0) ws[threadIdx.x >> 6] = r;
  __syncthreads();
  if (threadIdx.x == 0) bsum[blockIdx.x] = ws[0] + ws[1] + ws[2] + ws[3];
}

// ---------------- W split helper (bf16 hi + residual lo, frag layout) ----------------
__device__ __forceinline__ void wsplit_one(const float* __restrict__ W,
                                           short8* __restrict__ Wh,
                                           short8* __restrict__ Wl, int i) {
  int lane = i & 63, f = i >> 6;
  int kc = f >> 2, ct = f & 3;
  int kbase = kc * 32 + ((lane >> 4) << 3);
  int n = ct * 16 + (lane & 15);
  short8 h, l;
#pragma unroll
  for (int j = 0; j < 8; ++j) {
    float w = W[(size_t)(kbase + j) * HID + n];
    uint32_t u = __float_as_uint(w);
    h[j] = (short)(u >> 16);
    float r = w - __uint_as_float(u & 0xFFFF0000u);
    l[j] = (short)(__float_as_uint(r) >> 16);
  }
  Wh[i] = h;
  Wl[i] = l;
}

// ---- scan stage 2 (block 0) + the three W splits (blocks 1..8) in one dispatch ----
__global__ __launch_bounds__(1024) void k_scan2w(const int* __restrict__ bsum,
                                                 int* __restrict__ bpre, int B,
                                                 const float* __restrict__ W1,
                                                 short8* __restrict__ Wh1, short8* __restrict__ Wl1,
                                                 const float* __restrict__ W2,
                                                 short8* __restrict__ Wh2, short8* __restrict__ Wl2,
                                                 const float* __restrict__ W3,
                                                 short8* __restrict__ Wh3, short8* __restrict__ Wl3) {
  if (blockIdx.x == 0) {
    __shared__ int s[1024];
    int tid = threadIdx.x;
    int v = (tid < B) ? bsum[tid] : 0;
    s[tid] = v;
    __syncthreads();
    for (int off = 1; off < 1024; off <<= 1) {
      int t = (tid >= off) ? s[tid - off] : 0;
      __syncthreads();
      s[tid] += t;
      __syncthreads();
    }
    if (tid < B) bpre[tid] = s[tid] - v;  // exclusive
    return;
  }
  // blocks 1..8: 1024 threads each, but only 1024(W1)/512/512 entries needed
  int b = blockIdx.x - 1;
  int tid = threadIdx.x;
  if (b < 1) {                       // W1: KC=4 -> 1024 entries, block 1
    wsplit_one(W1, Wh1, Wl1, tid);
  } else if (b == 1 && tid < 512) {  // W2: KC=2 -> 512 entries
    wsplit_one(W2, Wh2, Wl2, tid);
  } else if (b == 2 && tid < 512) {  // W3
    wsplit_one(W3, Wh3, Wl3, tid);
  }
}

// ---- scan stage 3: local scan + offset -> row_off, cursor ----
__global__ __launch_bounds__(SCAN_B) void k_scan3(const int* __restrict__ counts,
                                                  const int* __restrict__ bpre,
                                                  int* __restrict__ row_off,
                                                  int* __restrict__ cursor,
                                                  int N, int E) {
  __shared__ int s[SCAN_B];
  int tid = threadIdx.x;
  int i = blockIdx.x * SCAN_B + tid;
  int v = (i < N) ? counts[i] : 0;
  s[tid] = v;
  __syncthreads();
  for (int off = 1; off < SCAN_B; off <<= 1) {
    int t = (tid >= off) ? s[tid - off] : 0;
    __syncthreads();
    s[tid] += t;
    __syncthreads();
  }
  if (i < N) {
    int excl = bpre[blockIdx.x] + s[tid] - v;
    row_off[i] = excl;
    cursor[i] = excl;
  }
  if (i == 0) row_off[N] = E;
}

// ---------------- fused CSR build + MFMA GEMM layer 1 ----------------
// Blocks [0, build_blocks): scatter packed (src, weight) into CSR slots.
// Blocks [build_blocks, +gemm_blocks): 64-row MFMA tile of C = A @ W.
// Both non-persistent -> co-resident; latency-bound build waves overlap the
// MFMA/VALU-bound gemm waves (round-5 failure was a persistent gemm grid).
template <int K>
__global__ __launch_bounds__(256) void k_mgemm_build(
    const float* __restrict__ A, const short8* __restrict__ Wh,
    const short8* __restrict__ Wl, float* __restrict__ C, int N,
    const int* __restrict__ src, const int* __restrict__ dst,
    const float* __restrict__ dinv, int* __restrict__ cursor,
    int2* __restrict__ csr, int E, int build_blocks) {
  if ((int)blockIdx.x < build_blocks) {
    int e = blockIdx.x * 256 + threadIdx.x;
    if (e < E) {
      int s = src[e], d = dst[e];
      int pos = atomicAdd(&cursor[d], 1);
      csr[pos] = make_int2(s, __float_as_int(dinv[s] * dinv[d]));
    }
    return;
  }
  constexpr int KC = K / 32;
  const int lane = threadIdx.x & 63;
  const int wv = threadIdx.x >> 6;
  const int m = lane & 15;
  const int q = lane >> 4;
  const int row0 = ((int)blockIdx.x - build_blocks) * 64 + wv * 16;
  if (row0 >= N) return;
  const int arow = min(row0 + m, N - 1);
  const float* __restrict__ ap = A + (size_t)arow * K + (q << 3);

  floatx4 acc[4];
#pragma unroll
  for (int ct = 0; ct < 4; ++ct) acc[ct] = (floatx4){0.f, 0.f, 0.f, 0.f};

#pragma unroll
  for (int kc = 0; kc < KC; ++kc) {
    const floatx4* apv = (const floatx4*)(ap + kc * 32);
    floatx4 x0 = apv[0];
    floatx4 x1 = apv[1];
    short8 ah, al;
#pragma unroll
    for (int j = 0; j < 4; ++j) {
      uint32_t u = __float_as_uint(x0[j]);
      ah[j] = (short)(u >> 16);
      float r = x0[j] - __uint_as_float(u & 0xFFFF0000u);
      al[j] = (short)(__float_as_uint(r) >> 16);
    }
#pragma unroll
    for (int j = 0; j < 4; ++j) {
      uint32_t u = __float_as_uint(x1[j]);
      ah[4 + j] = (short)(u >> 16);
      float r = x1[j] - __uint_as_float(u & 0xFFFF0000u);
      al[4 + j] = (short)(__float_as_uint(r) >> 16);
    }
#pragma unroll
    for (int ct = 0; ct < 4; ++ct) {
      short8 bh = Wh[(kc * 4 + ct) * 64 + lane];
      short8 bl = Wl[(kc * 4 + ct) * 64 + lane];
      acc[ct] = __builtin_amdgcn_mfma_f32_16x16x32_bf16(ah, bh, acc[ct], 0, 0, 0);
      acc[ct] = __builtin_amdgcn_mfma_f32_16x16x32_bf16(ah, bl, acc[ct], 0, 0, 0);
      acc[ct] = __builtin_amdgcn_mfma_f32_16x16x32_bf16(al, bh, acc[ct], 0, 0, 0);
    }
  }

  float* __restrict__ cp = C + (size_t)row0 * HID;
#pragma unroll
  for (int ct = 0; ct < 4; ++ct)
#pragma unroll
    for (int r = 0; r < 4; ++r) {
      int rr = (q << 2) + r;
      if (row0 + rr < N) cp[(size_t)rr * HID + ct * 16 + m] = acc[ct][r];
    }
}

// ---------------- MFMA GEMM (standalone, layers 2/3) ----------------
template <int K>
__global__ __launch_bounds__(256) void k_mgemm(const float* __restrict__ A,
                                               const short8* __restrict__ Wh,
                                               const short8* __restrict__ Wl,
                                               float* __restrict__ C, int N) {
  constexpr int KC = K / 32;
  const int lane = threadIdx.x & 63;
  const int wv = threadIdx.x >> 6;
  const int m = lane & 15;
  const int q = lane >> 4;
  const int row0 = blockIdx.x * 64 + wv * 16;
  if (row0 >= N) return;
  const int arow = min(row0 + m, N - 1);
  const float* __restrict__ ap = A + (size_t)arow * K + (q << 3);

  floatx4 acc[4];
#pragma unroll
  for (int ct = 0; ct < 4; ++ct) acc[ct] = (floatx4){0.f, 0.f, 0.f, 0.f};

#pragma unroll
  for (int kc = 0; kc < KC; ++kc) {
    const floatx4* apv = (const floatx4*)(ap + kc * 32);
    floatx4 x0 = apv[0];
    floatx4 x1 = apv[1];
    short8 ah, al;
#pragma unroll
    for (int j = 0; j < 4; ++j) {
      uint32_t u = __float_as_uint(x0[j]);
      ah[j] = (short)(u >> 16);
      float r = x0[j] - __uint_as_float(u & 0xFFFF0000u);
      al[j] = (short)(__float_as_uint(r) >> 16);
    }
#pragma unroll
    for (int j = 0; j < 4; ++j) {
      uint32_t u = __float_as_uint(x1[j]);
      ah[4 + j] = (short)(u >> 16);
      float r = x1[j] - __uint_as_float(u & 0xFFFF0000u);
      al[4 + j] = (short)(__float_as_uint(r) >> 16);
    }
#pragma unroll
    for (int ct = 0; ct < 4; ++ct) {
      short8 bh = Wh[(kc * 4 + ct) * 64 + lane];
      short8 bl = Wl[(kc * 4 + ct) * 64 + lane];
      acc[ct] = __builtin_amdgcn_mfma_f32_16x16x32_bf16(ah, bh, acc[ct], 0, 0, 0);
      acc[ct] = __builtin_amdgcn_mfma_f32_16x16x32_bf16(ah, bl, acc[ct], 0, 0, 0);
      acc[ct] = __builtin_amdgcn_mfma_f32_16x16x32_bf16(al, bh, acc[ct], 0, 0, 0);
    }
  }

  float* __restrict__ cp = C + (size_t)row0 * HID;
#pragma unroll
  for (int ct = 0; ct < 4; ++ct)
#pragma unroll
    for (int r = 0; r < 4; ++r) {
      int rr = (q << 2) + r;
      if (row0 + rr < N) cp[(size_t)rr * HID + ct * 16 + m] = acc[ct][r];
    }
}

// ---------------- fused gather + self-loop + bias + relu + dropout ----------------
__global__ __launch_bounds__(256) void k_gather(const float* __restrict__ tmp,
                                                const int* __restrict__ row_off,
                                                const int2* __restrict__ csr,
                                                const float* __restrict__ dinv,
                                                const float* __restrict__ bias,
                                                float* __restrict__ outh, int N,
                                                uint32_t k0, uint32_t k1) {
  const int node = blockIdx.x * 4 + (threadIdx.x >> 6);
  const int lane = threadIdx.x & 63;
  if (node >= N) return;
  const int beg = __builtin_amdgcn_readfirstlane(row_off[node]);
  const int end = __builtin_amdgcn_readfirstlane(row_off[node + 1]);
  float acc0 = 0.0f, acc1 = 0.0f, acc2 = 0.0f, acc3 = 0.0f;
  int j = beg;
  for (; j + 7 < end; j += 8) {
    int2 p0 = csr[j],     p1 = csr[j + 1], p2 = csr[j + 2], p3 = csr[j + 3];
    int2 p4 = csr[j + 4], p5 = csr[j + 5], p6 = csr[j + 6], p7 = csr[j + 7];
    float v0 = tmp[(size_t)p0.x * HID + lane];
    float v1 = tmp[(size_t)p1.x * HID + lane];
    float v2 = tmp[(size_t)p2.x * HID + lane];
    float v3 = tmp[(size_t)p3.x * HID + lane];
    float v4 = tmp[(size_t)p4.x * HID + lane];
    float v5 = tmp[(size_t)p5.x * HID + lane];
    float v6 = tmp[(size_t)p6.x * HID + lane];
    float v7 = tmp[(size_t)p7.x * HID + lane];
    acc0 = fmaf(v0, __int_as_float(p0.y), acc0);
    acc1 = fmaf(v1, __int_as_float(p1.y), acc1);
    acc2 = fmaf(v2, __int_as_float(p2.y), acc2);
    acc3 = fmaf(v3, __int_as_float(p3.y), acc3);
    acc0 = fmaf(v4, __int_as_float(p4.y), acc0);
    acc1 = fmaf(v5, __int_as_float(p5.y), acc1);
    acc2 = fmaf(v6, __int_as_float(p6.y), acc2);
    acc3 = fmaf(v7, __int_as_float(p7.y), acc3);
  }
  for (; j + 1 < end; j += 2) {
    int2 p0 = csr[j], p1 = csr[j + 1];
    float v0 = tmp[(size_t)p0.x * HID + lane];
    float v1 = tmp[(size_t)p1.x * HID + lane];
    acc0 = fmaf(v0, __int_as_float(p0.y), acc0);
    acc1 = fmaf(v1, __int_as_float(p1.y), acc1);
  }
  if (j < end) {
    int2 p0 = csr[j];
    acc2 = fmaf(tmp[(size_t)p0.x * HID + lane], __int_as_float(p0.y), acc2);
  }
  float acc = (acc0 + acc1) + (acc2 + acc3);
  const float dnode = dinv[node];
  const int idx = node * HID + lane;
  float v = acc + tmp[idx] * dnode * dnode + bias[lane];
  v = fmaxf(v, 0.0f);
  v = keep_mask(k0, k1, (uint32_t)idx) ? v / KEEPP : 0.0f;
  outh[idx] = v;
}

// ---------------- mean-pool partials ----------------
__global__ __launch_bounds__(256) void k_pool(const float* __restrict__ h,
                                              const int* __restrict__ batch,
                                              float* __restrict__ sums,
                                              float* __restrict__ cnts, int N) {
  __shared__ float ls[NGRAPH * HID];
  __shared__ float lc[NGRAPH];
  for (int i = threadIdx.x; i < NGRAPH * HID; i += 256) ls[i] = 0.0f;
  if (threadIdx.x < NGRAPH) lc[threadIdx.x] = 0.0f;
  __syncthreads();
  const int lane = threadIdx.x & 63;
  const int wave = threadIdx.x >> 6;
  int per = (N + gridDim.x - 1) / gridDim.x;
  int beg = blockIdx.x * per;
  int end = min(N, beg + per);
  for (int i = beg + wave; i < end; i += 4) {
    int g = batch[i];
    atomicAdd(&ls[g * HID + lane], h[(size_t)i * HID + lane]);
    if (lane == 0) atomicAdd(&lc[g], 1.0f);
  }
  __syncthreads();
  for (int i = threadIdx.x; i < NGRAPH * HID; i += 256)
    if (ls[i] != 0.0f) atomicAdd(&sums[i], ls[i]);
  if (threadIdx.x < NGRAPH && lc[threadIdx.x] != 0.0f)
    atomicAdd(&cnts[threadIdx.x], lc[threadIdx.x]);
}

// ---------------- MLP head (single block) ----------------
__global__ __launch_bounds__(256) void k_head(const float* __restrict__ sums,
                                              const float* __restrict__ cnts,
                                              const float* __restrict__ Wm1,
                                              const float* __restrict__ bm1,
                                              const float* __restrict__ Wm2,
                                              const float* __restrict__ bm2,
                                              float* __restrict__ out,
                                              uint32_t k0, uint32_t k1) {
  __shared__ float pooled[NGRAPH * HID];
  __shared__ float m[NGRAPH * HID];
  for (int i = threadIdx.x; i < NGRAPH * HID; i += 256) {
    int g = i >> 6;
    pooled[i] = sums[i] / fmaxf(cnts[g], 1.0f);
  }
  __syncthreads();
  for (int i = threadIdx.x; i < NGRAPH * HID; i += 256) {
    int g = i >> 6, j = i & 63;
    float acc = bm1[j];
#pragma unroll 8
    for (int k = 0; k < HID; ++k)
      acc = fmaf(pooled[g * HID + k], Wm1[k * HID + j], acc);
    acc = fmaxf(acc, 0.0f);
    m[i] = keep_mask(k0, k1, (uint32_t)i) ? acc / KEEPP : 0.0f;
  }
  __syncthreads();
  if (threadIdx.x < NGRAPH) {
    int g = threadIdx.x;
    float acc = bm2[0];
#pragma unroll 8
    for (int j = 0; j < HID; ++j)
      acc = fmaf(m[g * HID + j], Wm2[j], acc);
    out[g] = acc;
  }
}

extern "C" void kernel_launch(void* const* d_in, const int* in_sizes, int n_in,
                              void* d_out, int out_size, void* d_ws, size_t ws_size,
                              hipStream_t stream) {
  const float* x     = (const float*)d_in[0];
  const int*   ei    = (const int*)d_in[1];
  const int*   batch = (const int*)d_in[2];
  const float* W1 = (const float*)d_in[3];
  const float* b1 = (const float*)d_in[4];
  const float* W2 = (const float*)d_in[5];
  const float* b2 = (const float*)d_in[6];
  const float* W3 = (const float*)d_in[7];
  const float* b3 = (const float*)d_in[8];
  const float* Wm1 = (const float*)d_in[9];
  const float* bm1 = (const float*)d_in[10];
  const float* Wm2 = (const float*)d_in[11];
  const float* bm2 = (const float*)d_in[12];
  float* out = (float*)d_out;

  const int N = in_sizes[0] / INCH;
  const int E = in_sizes[1] / 2;
  const int* src = ei;
  const int* dst = ei + E;
  const int NB = (N + SCAN_B - 1) / SCAN_B;

  // workspace layout (all chunks >=16B-aligned)
  char* ws = (char*)d_ws;
  const size_t buf_bytes = (size_t)N * HID * sizeof(float);
  size_t off = 0;
  float* B0      = (float*)(ws + off); off += buf_bytes;
  float* B1      = (float*)(ws + off); off += buf_bytes;
  float* dinv    = (float*)(ws + off); off += (size_t)N * 4;
  int*   counts  = (int*)  (ws + off); off += (size_t)N * 4;
  int*   row_off = (int*)  (ws + off); off += ((size_t)N + 4) * 4;
  int*   cursor  = (int*)  (ws + off); off += (size_t)N * 4;
  int*   bsum    = (int*)  (ws + off); off += 1024 * 4;
  int*   bpre    = (int*)  (ws + off); off += 1024 * 4;
  int2*  csr     = (int2*) (ws + off); off += (size_t)E * 8;
  float* sums    = (float*)(ws + off); off += NGRAPH * HID * 4;
  float* cnts    = (float*)(ws + off); off += NGRAPH * 4;
  off = (off + 15) & ~(size_t)15;
  short8* Wh1 = (short8*)(ws + off); off += 1024 * 16;  // KC=4: 4*4*64 entries
  short8* Wl1 = (short8*)(ws + off); off += 1024 * 16;
  short8* Wh2 = (short8*)(ws + off); off += 512 * 16;   // KC=2
  short8* Wl2 = (short8*)(ws + off); off += 512 * 16;
  short8* Wh3 = (short8*)(ws + off); off += 512 * 16;
  short8* Wl3 = (short8*)(ws + off); off += 512 * 16;

  // dropout keys: dk[i] = threefry2x32((0,42),(0,i))
  uint32_t dk[4][2];
  for (uint32_t i = 0; i < 4; ++i) {
    uint32_t a = 0u, b = i;
    tf2x32(0u, 42u, a, b);
    dk[i][0] = a; dk[i][1] = b;
  }

  // ---- prelude: hist -> (scan1+dinv) -> (scan2 + wsplits) -> scan3 ----
  hipMemsetAsync(counts, 0, (size_t)N * sizeof(int), stream);
  k_hist<<<(E + 255) / 256, 256, 0, stream>>>(dst, E, counts);
  k_scan1d<<<NB, SCAN_B, 0, stream>>>(counts, bsum, dinv, N);
  k_scan2w<<<9, 1024, 0, stream>>>(bsum, bpre, NB,
                                   W1, Wh1, Wl1, W2, Wh2, Wl2, W3, Wh3, Wl3);
  k_scan3<<<NB, SCAN_B, 0, stream>>>(counts, bpre, row_off, cursor, N, E);

  const int build_grid = (E + 255) / 256;
  const int mg_grid    = (N + 63) / 64;
  const int gath_grid  = (N + 3) / 4;

  // ---- layer 1 (K=128) GEMM fused with CSR build ----
  k_mgemm_build<INCH><<<build_grid + mg_grid, 256, 0, stream>>>(
      x, Wh1, Wl1, B0, N, src, dst, dinv, cursor, csr, E, build_grid);
  k_gather<<<gath_grid, 256, 0, stream>>>(B0, row_off, csr, dinv, b1,
                                          B1, N, dk[0][0], dk[0][1]);
  // ---- layer 2 (K=64) ----
  k_mgemm<HID><<<mg_grid, 256, 0, stream>>>(B1, Wh2, Wl2, B0, N);
  k_gather<<<gath_grid, 256, 0, stream>>>(B0, row_off, csr, dinv, b2,
                                          B1, N, dk[1][0], dk[1][1]);
  // ---- layer 3 (K=64) ----
  k_mgemm<HID><<<mg_grid, 256, 0, stream>>>(B1, Wh3, Wl3, B0, N);
  k_gather<<<gath_grid, 256, 0, stream>>>(B0, row_off, csr, dinv, b3,
                                          B1, N, dk[2][0], dk[2][1]);

  // ---- pool + head ----
  hipMemsetAsync(sums, 0, (NGRAPH * HID + NGRAPH) * sizeof(float), stream);
  k_pool<<<256, 256, 0, stream>>>(B1, batch, sums, cnts, N);
  k_head<<<1, 256, 0, stream>>>(sums, cnts, Wm1, bm1, Wm2, bm2, out,
                                dk[3][0], dk[3][1]);
  (void)n_in; (void)out_size; (void)ws_size;
}

// Round 9
// 417.093 us; speedup vs baseline: 1.6991x; 1.1156x over previous
//
#include <hip/hip_runtime.h>
#include <stdint.h>

#define HID 64
#define INCH 128
#define NGRAPH 64
#define KEEPP 0.7f
#define SCAN_B 256   // elements per scan block

typedef __attribute__((ext_vector_type(8))) short short8;   // 8 bf16 = 4 VGPRs
typedef __attribute__((ext_vector_type(4))) float floatx4;  // MFMA acc
typedef unsigned short ushort_t;

// ---------------- bf16 helpers (RNE) ----------------
__device__ __forceinline__ ushort_t f2bf(float f) {
  uint32_t u = __float_as_uint(f);
  uint32_t r = u + 0x7FFFu + ((u >> 16) & 1u);
  return (ushort_t)(r >> 16);
}
__device__ __forceinline__ float bf2f(ushort_t h) {
  return __uint_as_float(((uint32_t)h) << 16);
}

// ---------------- Threefry-2x32 (JAX-compatible, 20 rounds) ----------------
__host__ __device__ inline void tf2x32(uint32_t k0, uint32_t k1,
                                       uint32_t& x0, uint32_t& x1) {
  const uint32_t ks2 = k0 ^ k1 ^ 0x1BD11BDAu;
#define ROTL32(v, d) (((v) << (d)) | ((v) >> (32 - (d))))
#define TF_RND(r) { x0 += x1; x1 = ROTL32(x1, r); x1 ^= x0; }
  x0 += k0; x1 += k1;
  TF_RND(13) TF_RND(15) TF_RND(26) TF_RND(6)
  x0 += k1;  x1 += ks2 + 1u;
  TF_RND(17) TF_RND(29) TF_RND(16) TF_RND(24)
  x0 += ks2; x1 += k0 + 2u;
  TF_RND(13) TF_RND(15) TF_RND(26) TF_RND(6)
  x0 += k0;  x1 += k1 + 3u;
  TF_RND(17) TF_RND(29) TF_RND(16) TF_RND(24)
  x0 += k1;  x1 += ks2 + 4u;
  TF_RND(13) TF_RND(15) TF_RND(26) TF_RND(6)
  x0 += ks2; x1 += k0 + 5u;
#undef TF_RND
#undef ROTL32
}

__device__ __forceinline__ bool keep_mask(uint32_t k0, uint32_t k1, uint32_t idx) {
  uint32_t x0 = 0u, x1 = idx;
  tf2x32(k0, k1, x0, x1);
  uint32_t bits = x0 ^ x1;
  float u = __uint_as_float((bits >> 9) | 0x3f800000u) - 1.0f;
  return u < KEEPP;
}

// ---------------- CSR build prelude ----------------
__global__ void k_hist(const int* __restrict__ dst, int E, int* __restrict__ counts) {
  int e = blockIdx.x * blockDim.x + threadIdx.x;
  if (e < E) atomicAdd(&counts[dst[e]], 1);
}

// ---- scan stage 1 + dinv fused (both read counts[i]) ----
__global__ __launch_bounds__(SCAN_B) void k_scan1d(const int* __restrict__ counts,
                                                   int* __restrict__ bsum,
                                                   float* __restrict__ dinv, int N) {
  int i = blockIdx.x * SCAN_B + threadIdx.x;
  int v = 0;
  if (i < N) {
    v = counts[i];
    dinv[i] = rsqrtf((float)v + 1.0f);  // in-degree + self-loop
  }
  int r = v;
  for (int off = 32; off > 0; off >>= 1) r += __shfl_down(r, off);
  __shared__ int ws[4];
  if ((threadIdx.x & 63) == 0) ws[threadIdx.x >> 6] = r;
  __syncthreads();
  if (threadIdx.x == 0) bsum[blockIdx.x] = ws[0] + ws[1] + ws[2] + ws[3];
}

// ---------------- W split helper (bf16 hi + residual lo, frag layout) ----------------
__device__ __forceinline__ void wsplit_one(const float* __restrict__ W,
                                           short8* __restrict__ Wh,
                                           short8* __restrict__ Wl, int i) {
  int lane = i & 63, f = i >> 6;
  int kc = f >> 2, ct = f & 3;
  int kbase = kc * 32 + ((lane >> 4) << 3);
  int n = ct * 16 + (lane & 15);
  short8 h, l;
#pragma unroll
  for (int j = 0; j < 8; ++j) {
    float w = W[(size_t)(kbase + j) * HID + n];
    uint32_t u = __float_as_uint(w);
    h[j] = (short)(u >> 16);
    float r = w - __uint_as_float(u & 0xFFFF0000u);
    l[j] = (short)(__float_as_uint(r) >> 16);
  }
  Wh[i] = h;
  Wl[i] = l;
}

// ---- scan stage 2 (block 0) + the three W splits (blocks 1..3) in one dispatch ----
__global__ __launch_bounds__(1024) void k_scan2w(const int* __restrict__ bsum,
                                                 int* __restrict__ bpre, int B,
                                                 const float* __restrict__ W1,
                                                 short8* __restrict__ Wh1, short8* __restrict__ Wl1,
                                                 const float* __restrict__ W2,
                                                 short8* __restrict__ Wh2, short8* __restrict__ Wl2,
                                                 const float* __restrict__ W3,
                                                 short8* __restrict__ Wh3, short8* __restrict__ Wl3) {
  if (blockIdx.x == 0) {
    __shared__ int s[1024];
    int tid = threadIdx.x;
    int v = (tid < B) ? bsum[tid] : 0;
    s[tid] = v;
    __syncthreads();
    for (int off = 1; off < 1024; off <<= 1) {
      int t = (tid >= off) ? s[tid - off] : 0;
      __syncthreads();
      s[tid] += t;
      __syncthreads();
    }
    if (tid < B) bpre[tid] = s[tid] - v;  // exclusive
    return;
  }
  int b = blockIdx.x - 1;
  int tid = threadIdx.x;
  if (b == 0) {                      // W1: KC=4 -> 1024 entries
    wsplit_one(W1, Wh1, Wl1, tid);
  } else if (b == 1 && tid < 512) {  // W2: KC=2 -> 512 entries
    wsplit_one(W2, Wh2, Wl2, tid);
  } else if (b == 2 && tid < 512) {  // W3
    wsplit_one(W3, Wh3, Wl3, tid);
  }
}

// ---- scan stage 3: local scan + offset -> row_off, cursor ----
__global__ __launch_bounds__(SCAN_B) void k_scan3(const int* __restrict__ counts,
                                                  const int* __restrict__ bpre,
                                                  int* __restrict__ row_off,
                                                  int* __restrict__ cursor,
                                                  int N, int E) {
  __shared__ int s[SCAN_B];
  int tid = threadIdx.x;
  int i = blockIdx.x * SCAN_B + tid;
  int v = (i < N) ? counts[i] : 0;
  s[tid] = v;
  __syncthreads();
  for (int off = 1; off < SCAN_B; off <<= 1) {
    int t = (tid >= off) ? s[tid - off] : 0;
    __syncthreads();
    s[tid] += t;
    __syncthreads();
  }
  if (i < N) {
    int excl = bpre[blockIdx.x] + s[tid] - v;
    row_off[i] = excl;
    cursor[i] = excl;
  }
  if (i == 0) row_off[N] = E;
}

// ---------------- MFMA gemm tile body (shared by fused & standalone) ----------------
template <int K>
__device__ __forceinline__ void mgemm_tile(const float* __restrict__ A,
                                           const short8* __restrict__ Wh,
                                           const short8* __restrict__ Wl,
                                           ushort_t* __restrict__ C, int N,
                                           int tile) {
  constexpr int KC = K / 32;
  const int lane = threadIdx.x & 63;
  const int wv = threadIdx.x >> 6;
  const int m = lane & 15;
  const int q = lane >> 4;
  const int row0 = tile * 64 + wv * 16;
  if (row0 >= N) return;
  const int arow = min(row0 + m, N - 1);
  const float* __restrict__ ap = A + (size_t)arow * K + (q << 3);

  floatx4 acc[4];
#pragma unroll
  for (int ct = 0; ct < 4; ++ct) acc[ct] = (floatx4){0.f, 0.f, 0.f, 0.f};

#pragma unroll
  for (int kc = 0; kc < KC; ++kc) {
    const floatx4* apv = (const floatx4*)(ap + kc * 32);
    floatx4 x0 = apv[0];
    floatx4 x1 = apv[1];
    short8 ah, al;
#pragma unroll
    for (int j = 0; j < 4; ++j) {
      uint32_t u = __float_as_uint(x0[j]);
      ah[j] = (short)(u >> 16);
      float r = x0[j] - __uint_as_float(u & 0xFFFF0000u);
      al[j] = (short)(__float_as_uint(r) >> 16);
    }
#pragma unroll
    for (int j = 0; j < 4; ++j) {
      uint32_t u = __float_as_uint(x1[j]);
      ah[4 + j] = (short)(u >> 16);
      float r = x1[j] - __uint_as_float(u & 0xFFFF0000u);
      al[4 + j] = (short)(__float_as_uint(r) >> 16);
    }
#pragma unroll
    for (int ct = 0; ct < 4; ++ct) {
      short8 bh = Wh[(kc * 4 + ct) * 64 + lane];
      short8 bl = Wl[(kc * 4 + ct) * 64 + lane];
      acc[ct] = __builtin_amdgcn_mfma_f32_16x16x32_bf16(ah, bh, acc[ct], 0, 0, 0);
      acc[ct] = __builtin_amdgcn_mfma_f32_16x16x32_bf16(ah, bl, acc[ct], 0, 0, 0);
      acc[ct] = __builtin_amdgcn_mfma_f32_16x16x32_bf16(al, bh, acc[ct], 0, 0, 0);
    }
  }

  ushort_t* __restrict__ cp = C + (size_t)row0 * HID;
#pragma unroll
  for (int ct = 0; ct < 4; ++ct)
#pragma unroll
    for (int r = 0; r < 4; ++r) {
      int rr = (q << 2) + r;
      if (row0 + rr < N) cp[(size_t)rr * HID + ct * 16 + m] = f2bf(acc[ct][r]);
    }
}

// ---------------- fused CSR build + MFMA GEMM layer 1 (Bresenham-interleaved) ----------------
// gemm tiles are spread 1-in-(T/mg) through the block sequence so build and
// gemm waves are co-resident from dispatch start (round-8 failure: gemm blocks
// were all at the end and only overlapped the build tail).
template <int K>
__global__ __launch_bounds__(256) void k_mgemm_build(
    const float* __restrict__ A, const short8* __restrict__ Wh,
    const short8* __restrict__ Wl, ushort_t* __restrict__ C, int N,
    const int* __restrict__ src, const int* __restrict__ dst,
    const float* __restrict__ dinv, int* __restrict__ cursor,
    int2* __restrict__ csr, int E, int build_blocks, int gemm_blocks) {
  const long T = (long)build_blocks + gemm_blocks;
  const long b = (long)blockIdx.x;
  const long gb = (b * gemm_blocks) / T;
  const bool is_g = (((b + 1) * gemm_blocks) / T) != gb;
  if (!is_g) {
    int bb = (int)(b - gb);
    int e = bb * 256 + (int)threadIdx.x;
    if (e < E) {
      int s = src[e], d = dst[e];
      int pos = atomicAdd(&cursor[d], 1);
      csr[pos] = make_int2(s, __float_as_int(dinv[s] * dinv[d]));
    }
    return;
  }
  mgemm_tile<K>(A, Wh, Wl, C, N, (int)gb);
}

// ---------------- MFMA GEMM (standalone, layers 2/3) ----------------
template <int K>
__global__ __launch_bounds__(256) void k_mgemm(const float* __restrict__ A,
                                               const short8* __restrict__ Wh,
                                               const short8* __restrict__ Wl,
                                               ushort_t* __restrict__ C, int N) {
  mgemm_tile<K>(A, Wh, Wl, C, N, (int)blockIdx.x);
}

// ---------------- fused gather + self-loop + bias + relu + dropout ----------------
// tmp is bf16 (128 B per row-read, half the line traffic of fp32).
__global__ __launch_bounds__(256) void k_gather(const ushort_t* __restrict__ tmp,
                                                const int* __restrict__ row_off,
                                                const int2* __restrict__ csr,
                                                const float* __restrict__ dinv,
                                                const float* __restrict__ bias,
                                                float* __restrict__ outh, int N,
                                                uint32_t k0, uint32_t k1) {
  const int node = blockIdx.x * 4 + (threadIdx.x >> 6);
  const int lane = threadIdx.x & 63;
  if (node >= N) return;
  const int beg = __builtin_amdgcn_readfirstlane(row_off[node]);
  const int end = __builtin_amdgcn_readfirstlane(row_off[node + 1]);
  float acc0 = 0.0f, acc1 = 0.0f, acc2 = 0.0f, acc3 = 0.0f;
  int j = beg;
  for (; j + 7 < end; j += 8) {
    int2 p0 = csr[j],     p1 = csr[j + 1], p2 = csr[j + 2], p3 = csr[j + 3];
    int2 p4 = csr[j + 4], p5 = csr[j + 5], p6 = csr[j + 6], p7 = csr[j + 7];
    float v0 = bf2f(tmp[(size_t)p0.x * HID + lane]);
    float v1 = bf2f(tmp[(size_t)p1.x * HID + lane]);
    float v2 = bf2f(tmp[(size_t)p2.x * HID + lane]);
    float v3 = bf2f(tmp[(size_t)p3.x * HID + lane]);
    float v4 = bf2f(tmp[(size_t)p4.x * HID + lane]);
    float v5 = bf2f(tmp[(size_t)p5.x * HID + lane]);
    float v6 = bf2f(tmp[(size_t)p6.x * HID + lane]);
    float v7 = bf2f(tmp[(size_t)p7.x * HID + lane]);
    acc0 = fmaf(v0, __int_as_float(p0.y), acc0);
    acc1 = fmaf(v1, __int_as_float(p1.y), acc1);
    acc2 = fmaf(v2, __int_as_float(p2.y), acc2);
    acc3 = fmaf(v3, __int_as_float(p3.y), acc3);
    acc0 = fmaf(v4, __int_as_float(p4.y), acc0);
    acc1 = fmaf(v5, __int_as_float(p5.y), acc1);
    acc2 = fmaf(v6, __int_as_float(p6.y), acc2);
    acc3 = fmaf(v7, __int_as_float(p7.y), acc3);
  }
  for (; j + 1 < end; j += 2) {
    int2 p0 = csr[j], p1 = csr[j + 1];
    float v0 = bf2f(tmp[(size_t)p0.x * HID + lane]);
    float v1 = bf2f(tmp[(size_t)p1.x * HID + lane]);
    acc0 = fmaf(v0, __int_as_float(p0.y), acc0);
    acc1 = fmaf(v1, __int_as_float(p1.y), acc1);
  }
  if (j < end) {
    int2 p0 = csr[j];
    acc2 = fmaf(bf2f(tmp[(size_t)p0.x * HID + lane]), __int_as_float(p0.y), acc2);
  }
  float acc = (acc0 + acc1) + (acc2 + acc3);
  const float dnode = dinv[node];
  const int idx = node * HID + lane;
  float v = acc + bf2f(tmp[idx]) * dnode * dnode + bias[lane];
  v = fmaxf(v, 0.0f);
  v = keep_mask(k0, k1, (uint32_t)idx) ? v / KEEPP : 0.0f;
  outh[idx] = v;
}

// ---------------- mean-pool partials ----------------
__global__ __launch_bounds__(256) void k_pool(const float* __restrict__ h,
                                              const int* __restrict__ batch,
                                              float* __restrict__ sums,
                                              float* __restrict__ cnts, int N) {
  __shared__ float ls[NGRAPH * HID];
  __shared__ float lc[NGRAPH];
  for (int i = threadIdx.x; i < NGRAPH * HID; i += 256) ls[i] = 0.0f;
  if (threadIdx.x < NGRAPH) lc[threadIdx.x] = 0.0f;
  __syncthreads();
  const int lane = threadIdx.x & 63;
  const int wave = threadIdx.x >> 6;
  int per = (N + gridDim.x - 1) / gridDim.x;
  int beg = blockIdx.x * per;
  int end = min(N, beg + per);
  for (int i = beg + wave; i < end; i += 4) {
    int g = batch[i];
    atomicAdd(&ls[g * HID + lane], h[(size_t)i * HID + lane]);
    if (lane == 0) atomicAdd(&lc[g], 1.0f);
  }
  __syncthreads();
  for (int i = threadIdx.x; i < NGRAPH * HID; i += 256)
    if (ls[i] != 0.0f) atomicAdd(&sums[i], ls[i]);
  if (threadIdx.x < NGRAPH && lc[threadIdx.x] != 0.0f)
    atomicAdd(&cnts[threadIdx.x], lc[threadIdx.x]);
}

// ---------------- MLP head (single block) ----------------
__global__ __launch_bounds__(256) void k_head(const float* __restrict__ sums,
                                              const float* __restrict__ cnts,
                                              const float* __restrict__ Wm1,
                                              const float* __restrict__ bm1,
                                              const float* __restrict__ Wm2,
                                              const float* __restrict__ bm2,
                                              float* __restrict__ out,
                                              uint32_t k0, uint32_t k1) {
  __shared__ float pooled[NGRAPH * HID];
  __shared__ float m[NGRAPH * HID];
  for (int i = threadIdx.x; i < NGRAPH * HID; i += 256) {
    int g = i >> 6;
    pooled[i] = sums[i] / fmaxf(cnts[g], 1.0f);
  }
  __syncthreads();
  for (int i = threadIdx.x; i < NGRAPH * HID; i += 256) {
    int g = i >> 6, j = i & 63;
    float acc = bm1[j];
#pragma unroll 8
    for (int k = 0; k < HID; ++k)
      acc = fmaf(pooled[g * HID + k], Wm1[k * HID + j], acc);
    acc = fmaxf(acc, 0.0f);
    m[i] = keep_mask(k0, k1, (uint32_t)i) ? acc / KEEPP : 0.0f;
  }
  __syncthreads();
  if (threadIdx.x < NGRAPH) {
    int g = threadIdx.x;
    float acc = bm2[0];
#pragma unroll 8
    for (int j = 0; j < HID; ++j)
      acc = fmaf(m[g * HID + j], Wm2[j], acc);
    out[g] = acc;
  }
}

extern "C" void kernel_launch(void* const* d_in, const int* in_sizes, int n_in,
                              void* d_out, int out_size, void* d_ws, size_t ws_size,
                              hipStream_t stream) {
  const float* x     = (const float*)d_in[0];
  const int*   ei    = (const int*)d_in[1];
  const int*   batch = (const int*)d_in[2];
  const float* W1 = (const float*)d_in[3];
  const float* b1 = (const float*)d_in[4];
  const float* W2 = (const float*)d_in[5];
  const float* b2 = (const float*)d_in[6];
  const float* W3 = (const float*)d_in[7];
  const float* b3 = (const float*)d_in[8];
  const float* Wm1 = (const float*)d_in[9];
  const float* bm1 = (const float*)d_in[10];
  const float* Wm2 = (const float*)d_in[11];
  const float* bm2 = (const float*)d_in[12];
  float* out = (float*)d_out;

  const int N = in_sizes[0] / INCH;
  const int E = in_sizes[1] / 2;
  const int* src = ei;
  const int* dst = ei + E;
  const int NB = (N + SCAN_B - 1) / SCAN_B;

  // workspace layout (all chunks >=16B-aligned)
  char* ws = (char*)d_ws;
  size_t off = 0;
  ushort_t* B0 = (ushort_t*)(ws + off); off += (size_t)N * HID * 2;      // bf16 tmp
  off = (off + 15) & ~(size_t)15;
  float* B1      = (float*)(ws + off); off += (size_t)N * HID * 4;       // fp32 h
  float* dinv    = (float*)(ws + off); off += (size_t)N * 4;
  int*   counts  = (int*)  (ws + off); off += (size_t)N * 4;
  int*   row_off = (int*)  (ws + off); off += ((size_t)N + 4) * 4;
  int*   cursor  = (int*)  (ws + off); off += (size_t)N * 4;
  int*   bsum    = (int*)  (ws + off); off += 1024 * 4;
  int*   bpre    = (int*)  (ws + off); off += 1024 * 4;
  int2*  csr     = (int2*) (ws + off); off += (size_t)E * 8;
  float* sums    = (float*)(ws + off); off += NGRAPH * HID * 4;
  float* cnts    = (float*)(ws + off); off += NGRAPH * 4;
  off = (off + 15) & ~(size_t)15;
  short8* Wh1 = (short8*)(ws + off); off += 1024 * 16;  // KC=4: 4*4*64 entries
  short8* Wl1 = (short8*)(ws + off); off += 1024 * 16;
  short8* Wh2 = (short8*)(ws + off); off += 512 * 16;   // KC=2
  short8* Wl2 = (short8*)(ws + off); off += 512 * 16;
  short8* Wh3 = (short8*)(ws + off); off += 512 * 16;
  short8* Wl3 = (short8*)(ws + off); off += 512 * 16;

  // dropout keys: dk[i] = threefry2x32((0,42),(0,i))
  uint32_t dk[4][2];
  for (uint32_t i = 0; i < 4; ++i) {
    uint32_t a = 0u, b = i;
    tf2x32(0u, 42u, a, b);
    dk[i][0] = a; dk[i][1] = b;
  }

  // ---- prelude: hist -> (scan1+dinv) -> (scan2 + wsplits) -> scan3 ----
  hipMemsetAsync(counts, 0, (size_t)N * sizeof(int), stream);
  k_hist<<<(E + 255) / 256, 256, 0, stream>>>(dst, E, counts);
  k_scan1d<<<NB, SCAN_B, 0, stream>>>(counts, bsum, dinv, N);
  k_scan2w<<<4, 1024, 0, stream>>>(bsum, bpre, NB,
                                   W1, Wh1, Wl1, W2, Wh2, Wl2, W3, Wh3, Wl3);
  k_scan3<<<NB, SCAN_B, 0, stream>>>(counts, bpre, row_off, cursor, N, E);

  const int build_grid = (E + 255) / 256;
  const int mg_grid    = (N + 63) / 64;
  const int gath_grid  = (N + 3) / 4;

  // ---- layer 1 (K=128) GEMM fused with CSR build (interleaved roles) ----
  k_mgemm_build<INCH><<<build_grid + mg_grid, 256, 0, stream>>>(
      x, Wh1, Wl1, B0, N, src, dst, dinv, cursor, csr, E, build_grid, mg_grid);
  k_gather<<<gath_grid, 256, 0, stream>>>(B0, row_off, csr, dinv, b1,
                                          B1, N, dk[0][0], dk[0][1]);
  // ---- layer 2 (K=64) ----
  k_mgemm<HID><<<mg_grid, 256, 0, stream>>>(B1, Wh2, Wl2, B0, N);
  k_gather<<<gath_grid, 256, 0, stream>>>(B0, row_off, csr, dinv, b2,
                                          B1, N, dk[1][0], dk[1][1]);
  // ---- layer 3 (K=64) ----
  k_mgemm<HID><<<mg_grid, 256, 0, stream>>>(B1, Wh3, Wl3, B0, N);
  k_gather<<<gath_grid, 256, 0, stream>>>(B0, row_off, csr, dinv, b3,
                                          B1, N, dk[2][0], dk[2][1]);

  // ---- pool + head ----
  hipMemsetAsync(sums, 0, (NGRAPH * HID + NGRAPH) * sizeof(float), stream);
  k_pool<<<256, 256, 0, stream>>>(B1, batch, sums, cnts, N);
  k_head<<<1, 256, 0, stream>>>(sums, cnts, Wm1, bm1, Wm2, bm2, out,
                                dk[3][0], dk[3][1]);
  (void)n_in; (void)out_size; (void)ws_size;
}

// Round 10
// 410.257 us; speedup vs baseline: 1.7274x; 1.0167x over previous
//
#include <hip/hip_runtime.h>
#include <hip/hip_fp8.h>
#include <stdint.h>

#define HID 64
#define INCH 128
#define NGRAPH 64
#define KEEPP 0.7f
#define SCAN_B 256   // elements per scan block

typedef __attribute__((ext_vector_type(8))) short short8;   // 8 bf16 = 4 VGPRs
typedef __attribute__((ext_vector_type(4))) float floatx4;  // MFMA acc
typedef unsigned short ushort_t;

// ---------------- fp8 e4m3 (OCP) helpers — HW cvt on gfx950 ----------------
__device__ __forceinline__ uint8_t f2e4(float f) {
  __hip_fp8_e4m3 t(f);
  return (uint8_t)t.__x;
}
__device__ __forceinline__ float e42f(uint8_t b) {
  __hip_fp8_e4m3 t;
  t.__x = (__hip_fp8_storage_t)b;
  return (float)t;
}

// ---------------- Threefry-2x32 (JAX-compatible, 20 rounds) ----------------
__host__ __device__ inline void tf2x32(uint32_t k0, uint32_t k1,
                                       uint32_t& x0, uint32_t& x1) {
  const uint32_t ks2 = k0 ^ k1 ^ 0x1BD11BDAu;
#define ROTL32(v, d) (((v) << (d)) | ((v) >> (32 - (d))))
#define TF_RND(r) { x0 += x1; x1 = ROTL32(x1, r); x1 ^= x0; }
  x0 += k0; x1 += k1;
  TF_RND(13) TF_RND(15) TF_RND(26) TF_RND(6)
  x0 += k1;  x1 += ks2 + 1u;
  TF_RND(17) TF_RND(29) TF_RND(16) TF_RND(24)
  x0 += ks2; x1 += k0 + 2u;
  TF_RND(13) TF_RND(15) TF_RND(26) TF_RND(6)
  x0 += k0;  x1 += k1 + 3u;
  TF_RND(17) TF_RND(29) TF_RND(16) TF_RND(24)
  x0 += k1;  x1 += ks2 + 4u;
  TF_RND(13) TF_RND(15) TF_RND(26) TF_RND(6)
  x0 += ks2; x1 += k0 + 5u;
#undef TF_RND
#undef ROTL32
}

__device__ __forceinline__ bool keep_mask(uint32_t k0, uint32_t k1, uint32_t idx) {
  uint32_t x0 = 0u, x1 = idx;
  tf2x32(k0, k1, x0, x1);
  uint32_t bits = x0 ^ x1;
  float u = __uint_as_float((bits >> 9) | 0x3f800000u) - 1.0f;
  return u < KEEPP;
}

// ---------------- CSR build prelude ----------------
__global__ void k_hist(const int* __restrict__ dst, int E, int* __restrict__ counts) {
  int e = blockIdx.x * blockDim.x + threadIdx.x;
  if (e < E) atomicAdd(&counts[dst[e]], 1);
}

// ---- scan stage 1 + dinv fused (both read counts[i]) ----
__global__ __launch_bounds__(SCAN_B) void k_scan1d(const int* __restrict__ counts,
                                                   int* __restrict__ bsum,
                                                   float* __restrict__ dinv, int N) {
  int i = blockIdx.x * SCAN_B + threadIdx.x;
  int v = 0;
  if (i < N) {
    v = counts[i];
    dinv[i] = rsqrtf((float)v + 1.0f);  // in-degree + self-loop
  }
  int r = v;
  for (int off = 32; off > 0; off >>= 1) r += __shfl_down(r, off);
  __shared__ int ws[4];
  if ((threadIdx.x & 63) == 0) ws[threadIdx.x >> 6] = r;
  __syncthreads();
  if (threadIdx.x == 0) bsum[blockIdx.x] = ws[0] + ws[1] + ws[2] + ws[3];
}

// ---------------- W split helper (bf16 hi + residual lo, frag layout) ----------------
__device__ __forceinline__ void wsplit_one(const float* __restrict__ W,
                                           short8* __restrict__ Wh,
                                           short8* __restrict__ Wl, int i) {
  int lane = i & 63, f = i >> 6;
  int kc = f >> 2, ct = f & 3;
  int kbase = kc * 32 + ((lane >> 4) << 3);
  int n = ct * 16 + (lane & 15);
  short8 h, l;
#pragma unroll
  for (int j = 0; j < 8; ++j) {
    float w = W[(size_t)(kbase + j) * HID + n];
    uint32_t u = __float_as_uint(w);
    h[j] = (short)(u >> 16);
    float r = w - __uint_as_float(u & 0xFFFF0000u);
    l[j] = (short)(__float_as_uint(r) >> 16);
  }
  Wh[i] = h;
  Wl[i] = l;
}

// ---- scan stage 2 (block 0) + the three W splits (blocks 1..3) in one dispatch ----
__global__ __launch_bounds__(1024) void k_scan2w(const int* __restrict__ bsum,
                                                 int* __restrict__ bpre, int B,
                                                 const float* __restrict__ W1,
                                                 short8* __restrict__ Wh1, short8* __restrict__ Wl1,
                                                 const float* __restrict__ W2,
                                                 short8* __restrict__ Wh2, short8* __restrict__ Wl2,
                                                 const float* __restrict__ W3,
                                                 short8* __restrict__ Wh3, short8* __restrict__ Wl3) {
  if (blockIdx.x == 0) {
    __shared__ int s[1024];
    int tid = threadIdx.x;
    int v = (tid < B) ? bsum[tid] : 0;
    s[tid] = v;
    __syncthreads();
    for (int off = 1; off < 1024; off <<= 1) {
      int t = (tid >= off) ? s[tid - off] : 0;
      __syncthreads();
      s[tid] += t;
      __syncthreads();
    }
    if (tid < B) bpre[tid] = s[tid] - v;  // exclusive
    return;
  }
  int b = blockIdx.x - 1;
  int tid = threadIdx.x;
  if (b == 0) {                      // W1: KC=4 -> 1024 entries
    wsplit_one(W1, Wh1, Wl1, tid);
  } else if (b == 1 && tid < 512) {  // W2: KC=2 -> 512 entries
    wsplit_one(W2, Wh2, Wl2, tid);
  } else if (b == 2 && tid < 512) {  // W3
    wsplit_one(W3, Wh3, Wl3, tid);
  }
}

// ---- scan stage 3: local scan + offset -> row_off, cursor ----
__global__ __launch_bounds__(SCAN_B) void k_scan3(const int* __restrict__ counts,
                                                  const int* __restrict__ bpre,
                                                  int* __restrict__ row_off,
                                                  int* __restrict__ cursor,
                                                  int N, int E) {
  __shared__ int s[SCAN_B];
  int tid = threadIdx.x;
  int i = blockIdx.x * SCAN_B + tid;
  int v = (i < N) ? counts[i] : 0;
  s[tid] = v;
  __syncthreads();
  for (int off = 1; off < SCAN_B; off <<= 1) {
    int t = (tid >= off) ? s[tid - off] : 0;
    __syncthreads();
    s[tid] += t;
    __syncthreads();
  }
  if (i < N) {
    int excl = bpre[blockIdx.x] + s[tid] - v;
    row_off[i] = excl;
    cursor[i] = excl;
  }
  if (i == 0) row_off[N] = E;
}

// ---------------- MFMA gemm tile body (shared by fused & standalone) ----------------
// Output C is fp8 e4m3 (the only consumer is the gather; 1 line per row).
template <int K>
__device__ __forceinline__ void mgemm_tile(const float* __restrict__ A,
                                           const short8* __restrict__ Wh,
                                           const short8* __restrict__ Wl,
                                           uint8_t* __restrict__ C, int N,
                                           int tile) {
  constexpr int KC = K / 32;
  const int lane = threadIdx.x & 63;
  const int wv = threadIdx.x >> 6;
  const int m = lane & 15;
  const int q = lane >> 4;
  const int row0 = tile * 64 + wv * 16;
  if (row0 >= N) return;
  const int arow = min(row0 + m, N - 1);
  const float* __restrict__ ap = A + (size_t)arow * K + (q << 3);

  floatx4 acc[4];
#pragma unroll
  for (int ct = 0; ct < 4; ++ct) acc[ct] = (floatx4){0.f, 0.f, 0.f, 0.f};

#pragma unroll
  for (int kc = 0; kc < KC; ++kc) {
    const floatx4* apv = (const floatx4*)(ap + kc * 32);
    floatx4 x0 = apv[0];
    floatx4 x1 = apv[1];
    short8 ah, al;
#pragma unroll
    for (int j = 0; j < 4; ++j) {
      uint32_t u = __float_as_uint(x0[j]);
      ah[j] = (short)(u >> 16);
      float r = x0[j] - __uint_as_float(u & 0xFFFF0000u);
      al[j] = (short)(__float_as_uint(r) >> 16);
    }
#pragma unroll
    for (int j = 0; j < 4; ++j) {
      uint32_t u = __float_as_uint(x1[j]);
      ah[4 + j] = (short)(u >> 16);
      float r = x1[j] - __uint_as_float(u & 0xFFFF0000u);
      al[4 + j] = (short)(__float_as_uint(r) >> 16);
    }
#pragma unroll
    for (int ct = 0; ct < 4; ++ct) {
      short8 bh = Wh[(kc * 4 + ct) * 64 + lane];
      short8 bl = Wl[(kc * 4 + ct) * 64 + lane];
      acc[ct] = __builtin_amdgcn_mfma_f32_16x16x32_bf16(ah, bh, acc[ct], 0, 0, 0);
      acc[ct] = __builtin_amdgcn_mfma_f32_16x16x32_bf16(ah, bl, acc[ct], 0, 0, 0);
      acc[ct] = __builtin_amdgcn_mfma_f32_16x16x32_bf16(al, bh, acc[ct], 0, 0, 0);
    }
  }

  uint8_t* __restrict__ cp = C + (size_t)row0 * HID;
#pragma unroll
  for (int ct = 0; ct < 4; ++ct)
#pragma unroll
    for (int r = 0; r < 4; ++r) {
      int rr = (q << 2) + r;
      if (row0 + rr < N) cp[(size_t)rr * HID + ct * 16 + m] = f2e4(acc[ct][r]);
    }
}

// ---------------- fused CSR build + MFMA GEMM layer 1 (Bresenham-interleaved) ----------------
template <int K>
__global__ __launch_bounds__(256) void k_mgemm_build(
    const float* __restrict__ A, const short8* __restrict__ Wh,
    const short8* __restrict__ Wl, uint8_t* __restrict__ C, int N,
    const int* __restrict__ src, const int* __restrict__ dst,
    const float* __restrict__ dinv, int* __restrict__ cursor,
    int2* __restrict__ csr, int E, int build_blocks, int gemm_blocks) {
  const long T = (long)build_blocks + gemm_blocks;
  const long b = (long)blockIdx.x;
  const long gb = (b * gemm_blocks) / T;
  const bool is_g = (((b + 1) * gemm_blocks) / T) != gb;
  if (!is_g) {
    int bb = (int)(b - gb);
    int e = bb * 256 + (int)threadIdx.x;
    if (e < E) {
      int s = src[e], d = dst[e];
      int pos = atomicAdd(&cursor[d], 1);
      csr[pos] = make_int2(s, __float_as_int(dinv[s] * dinv[d]));
    }
    return;
  }
  mgemm_tile<K>(A, Wh, Wl, C, N, (int)gb);
}

// ---------------- MFMA GEMM (standalone, layers 2/3) ----------------
template <int K>
__global__ __launch_bounds__(256) void k_mgemm(const float* __restrict__ A,
                                               const short8* __restrict__ Wh,
                                               const short8* __restrict__ Wl,
                                               uint8_t* __restrict__ C, int N) {
  mgemm_tile<K>(A, Wh, Wl, C, N, (int)blockIdx.x);
}

// ---------------- fused gather + self-loop + bias + relu + dropout ----------------
// tmp is fp8 e4m3: a random row read = 64 B = exactly one cache line.
__global__ __launch_bounds__(256) void k_gather(const uint8_t* __restrict__ tmp,
                                                const int* __restrict__ row_off,
                                                const int2* __restrict__ csr,
                                                const float* __restrict__ dinv,
                                                const float* __restrict__ bias,
                                                float* __restrict__ outh, int N,
                                                uint32_t k0, uint32_t k1) {
  const int node = blockIdx.x * 4 + (threadIdx.x >> 6);
  const int lane = threadIdx.x & 63;
  if (node >= N) return;
  const int beg = __builtin_amdgcn_readfirstlane(row_off[node]);
  const int end = __builtin_amdgcn_readfirstlane(row_off[node + 1]);
  float acc0 = 0.0f, acc1 = 0.0f, acc2 = 0.0f, acc3 = 0.0f;
  int j = beg;
  for (; j + 7 < end; j += 8) {
    int2 p0 = csr[j],     p1 = csr[j + 1], p2 = csr[j + 2], p3 = csr[j + 3];
    int2 p4 = csr[j + 4], p5 = csr[j + 5], p6 = csr[j + 6], p7 = csr[j + 7];
    float v0 = e42f(tmp[(size_t)p0.x * HID + lane]);
    float v1 = e42f(tmp[(size_t)p1.x * HID + lane]);
    float v2 = e42f(tmp[(size_t)p2.x * HID + lane]);
    float v3 = e42f(tmp[(size_t)p3.x * HID + lane]);
    float v4 = e42f(tmp[(size_t)p4.x * HID + lane]);
    float v5 = e42f(tmp[(size_t)p5.x * HID + lane]);
    float v6 = e42f(tmp[(size_t)p6.x * HID + lane]);
    float v7 = e42f(tmp[(size_t)p7.x * HID + lane]);
    acc0 = fmaf(v0, __int_as_float(p0.y), acc0);
    acc1 = fmaf(v1, __int_as_float(p1.y), acc1);
    acc2 = fmaf(v2, __int_as_float(p2.y), acc2);
    acc3 = fmaf(v3, __int_as_float(p3.y), acc3);
    acc0 = fmaf(v4, __int_as_float(p4.y), acc0);
    acc1 = fmaf(v5, __int_as_float(p5.y), acc1);
    acc2 = fmaf(v6, __int_as_float(p6.y), acc2);
    acc3 = fmaf(v7, __int_as_float(p7.y), acc3);
  }
  for (; j + 1 < end; j += 2) {
    int2 p0 = csr[j], p1 = csr[j + 1];
    float v0 = e42f(tmp[(size_t)p0.x * HID + lane]);
    float v1 = e42f(tmp[(size_t)p1.x * HID + lane]);
    acc0 = fmaf(v0, __int_as_float(p0.y), acc0);
    acc1 = fmaf(v1, __int_as_float(p1.y), acc1);
  }
  if (j < end) {
    int2 p0 = csr[j];
    acc2 = fmaf(e42f(tmp[(size_t)p0.x * HID + lane]), __int_as_float(p0.y), acc2);
  }
  float acc = (acc0 + acc1) + (acc2 + acc3);
  const float dnode = dinv[node];
  const int idx = node * HID + lane;
  float v = acc + e42f(tmp[idx]) * dnode * dnode + bias[lane];
  v = fmaxf(v, 0.0f);
  v = keep_mask(k0, k1, (uint32_t)idx) ? v / KEEPP : 0.0f;
  outh[idx] = v;
}

// ---------------- mean-pool partials ----------------
__global__ __launch_bounds__(256) void k_pool(const float* __restrict__ h,
                                              const int* __restrict__ batch,
                                              float* __restrict__ sums,
                                              float* __restrict__ cnts, int N) {
  __shared__ float ls[NGRAPH * HID];
  __shared__ float lc[NGRAPH];
  for (int i = threadIdx.x; i < NGRAPH * HID; i += 256) ls[i] = 0.0f;
  if (threadIdx.x < NGRAPH) lc[threadIdx.x] = 0.0f;
  __syncthreads();
  const int lane = threadIdx.x & 63;
  const int wave = threadIdx.x >> 6;
  int per = (N + gridDim.x - 1) / gridDim.x;
  int beg = blockIdx.x * per;
  int end = min(N, beg + per);
  for (int i = beg + wave; i < end; i += 4) {
    int g = batch[i];
    atomicAdd(&ls[g * HID + lane], h[(size_t)i * HID + lane]);
    if (lane == 0) atomicAdd(&lc[g], 1.0f);
  }
  __syncthreads();
  for (int i = threadIdx.x; i < NGRAPH * HID; i += 256)
    if (ls[i] != 0.0f) atomicAdd(&sums[i], ls[i]);
  if (threadIdx.x < NGRAPH && lc[threadIdx.x] != 0.0f)
    atomicAdd(&cnts[threadIdx.x], lc[threadIdx.x]);
}

// ---------------- MLP head (single block) ----------------
__global__ __launch_bounds__(256) void k_head(const float* __restrict__ sums,
                                              const float* __restrict__ cnts,
                                              const float* __restrict__ Wm1,
                                              const float* __restrict__ bm1,
                                              const float* __restrict__ Wm2,
                                              const float* __restrict__ bm2,
                                              float* __restrict__ out,
                                              uint32_t k0, uint32_t k1) {
  __shared__ float pooled[NGRAPH * HID];
  __shared__ float m[NGRAPH * HID];
  for (int i = threadIdx.x; i < NGRAPH * HID; i += 256) {
    int g = i >> 6;
    pooled[i] = sums[i] / fmaxf(cnts[g], 1.0f);
  }
  __syncthreads();
  for (int i = threadIdx.x; i < NGRAPH * HID; i += 256) {
    int g = i >> 6, j = i & 63;
    float acc = bm1[j];
#pragma unroll 8
    for (int k = 0; k < HID; ++k)
      acc = fmaf(pooled[g * HID + k], Wm1[k * HID + j], acc);
    acc = fmaxf(acc, 0.0f);
    m[i] = keep_mask(k0, k1, (uint32_t)i) ? acc / KEEPP : 0.0f;
  }
  __syncthreads();
  if (threadIdx.x < NGRAPH) {
    int g = threadIdx.x;
    float acc = bm2[0];
#pragma unroll 8
    for (int j = 0; j < HID; ++j)
      acc = fmaf(m[g * HID + j], Wm2[j], acc);
    out[g] = acc;
  }
}

extern "C" void kernel_launch(void* const* d_in, const int* in_sizes, int n_in,
                              void* d_out, int out_size, void* d_ws, size_t ws_size,
                              hipStream_t stream) {
  const float* x     = (const float*)d_in[0];
  const int*   ei    = (const int*)d_in[1];
  const int*   batch = (const int*)d_in[2];
  const float* W1 = (const float*)d_in[3];
  const float* b1 = (const float*)d_in[4];
  const float* W2 = (const float*)d_in[5];
  const float* b2 = (const float*)d_in[6];
  const float* W3 = (const float*)d_in[7];
  const float* b3 = (const float*)d_in[8];
  const float* Wm1 = (const float*)d_in[9];
  const float* bm1 = (const float*)d_in[10];
  const float* Wm2 = (const float*)d_in[11];
  const float* bm2 = (const float*)d_in[12];
  float* out = (float*)d_out;

  const int N = in_sizes[0] / INCH;
  const int E = in_sizes[1] / 2;
  const int* src = ei;
  const int* dst = ei + E;
  const int NB = (N + SCAN_B - 1) / SCAN_B;

  // workspace layout (all chunks >=16B-aligned)
  char* ws = (char*)d_ws;
  size_t off = 0;
  uint8_t* B0 = (uint8_t*)(ws + off); off += (size_t)N * HID;            // fp8 tmp
  off = (off + 15) & ~(size_t)15;
  float* B1      = (float*)(ws + off); off += (size_t)N * HID * 4;       // fp32 h
  float* dinv    = (float*)(ws + off); off += (size_t)N * 4;
  int*   counts  = (int*)  (ws + off); off += (size_t)N * 4;
  int*   row_off = (int*)  (ws + off); off += ((size_t)N + 4) * 4;
  int*   cursor  = (int*)  (ws + off); off += (size_t)N * 4;
  int*   bsum    = (int*)  (ws + off); off += 1024 * 4;
  int*   bpre    = (int*)  (ws + off); off += 1024 * 4;
  int2*  csr     = (int2*) (ws + off); off += (size_t)E * 8;
  float* sums    = (float*)(ws + off); off += NGRAPH * HID * 4;
  float* cnts    = (float*)(ws + off); off += NGRAPH * 4;
  off = (off + 15) & ~(size_t)15;
  short8* Wh1 = (short8*)(ws + off); off += 1024 * 16;  // KC=4: 4*4*64 entries
  short8* Wl1 = (short8*)(ws + off); off += 1024 * 16;
  short8* Wh2 = (short8*)(ws + off); off += 512 * 16;   // KC=2
  short8* Wl2 = (short8*)(ws + off); off += 512 * 16;
  short8* Wh3 = (short8*)(ws + off); off += 512 * 16;
  short8* Wl3 = (short8*)(ws + off); off += 512 * 16;

  // dropout keys: dk[i] = threefry2x32((0,42),(0,i))
  uint32_t dk[4][2];
  for (uint32_t i = 0; i < 4; ++i) {
    uint32_t a = 0u, b = i;
    tf2x32(0u, 42u, a, b);
    dk[i][0] = a; dk[i][1] = b;
  }

  // ---- prelude: hist -> (scan1+dinv) -> (scan2 + wsplits) -> scan3 ----
  hipMemsetAsync(counts, 0, (size_t)N * sizeof(int), stream);
  k_hist<<<(E + 255) / 256, 256, 0, stream>>>(dst, E, counts);
  k_scan1d<<<NB, SCAN_B, 0, stream>>>(counts, bsum, dinv, N);
  k_scan2w<<<4, 1024, 0, stream>>>(bsum, bpre, NB,
                                   W1, Wh1, Wl1, W2, Wh2, Wl2, W3, Wh3, Wl3);
  k_scan3<<<NB, SCAN_B, 0, stream>>>(counts, bpre, row_off, cursor, N, E);

  const int build_grid = (E + 255) / 256;
  const int mg_grid    = (N + 63) / 64;
  const int gath_grid  = (N + 3) / 4;

  // ---- layer 1 (K=128) GEMM fused with CSR build (interleaved roles) ----
  k_mgemm_build<INCH><<<build_grid + mg_grid, 256, 0, stream>>>(
      x, Wh1, Wl1, B0, N, src, dst, dinv, cursor, csr, E, build_grid, mg_grid);
  k_gather<<<gath_grid, 256, 0, stream>>>(B0, row_off, csr, dinv, b1,
                                          B1, N, dk[0][0], dk[0][1]);
  // ---- layer 2 (K=64) ----
  k_mgemm<HID><<<mg_grid, 256, 0, stream>>>(B1, Wh2, Wl2, B0, N);
  k_gather<<<gath_grid, 256, 0, stream>>>(B0, row_off, csr, dinv, b2,
                                          B1, N, dk[1][0], dk[1][1]);
  // ---- layer 3 (K=64) ----
  k_mgemm<HID><<<mg_grid, 256, 0, stream>>>(B1, Wh3, Wl3, B0, N);
  k_gather<<<gath_grid, 256, 0, stream>>>(B0, row_off, csr, dinv, b3,
                                          B1, N, dk[2][0], dk[2][1]);

  // ---- pool + head ----
  hipMemsetAsync(sums, 0, (NGRAPH * HID + NGRAPH) * sizeof(float), stream);
  k_pool<<<256, 256, 0, stream>>>(B1, batch, sums, cnts, N);
  k_head<<<1, 256, 0, stream>>>(sums, cnts, Wm1, bm1, Wm2, bm2, out,
                                dk[3][0], dk[3][1]);
  (void)n_in; (void)out_size; (void)ws_size;
}